// Round 12
// baseline (303.837 us; speedup 1.0000x reference)
//
#include <hip/hip_runtime.h>
#include <hip/hip_bf16.h>
#include <cstdint>

typedef __attribute__((ext_vector_type(8))) short short8;
typedef __attribute__((ext_vector_type(4))) float f32x4;

__device__ __forceinline__ uint16_t f2b(float f) {
  uint32_t u = __builtin_bit_cast(uint32_t, f);
  return (uint16_t)((u + 0x7FFFu + ((u >> 16) & 1u)) >> 16);
}
__device__ __forceinline__ float b2f(uint16_t h) {
  uint32_t u = ((uint32_t)h) << 16;
  return __builtin_bit_cast(float, u);
}
// async global->LDS, 16B per lane. LDS dest must be wave-uniform base + lane*16.
__device__ __forceinline__ void async16(void* lds, const void* g) {
  __builtin_amdgcn_global_load_lds(
      (const __attribute__((address_space(1))) uint32_t*)g,
      (__attribute__((address_space(3))) uint32_t*)lds, 16, 0, 0);
}
// T1: XCD-chunked bijective remap (nwg % 8 == 0 for all our MFMA grids).
__device__ __forceinline__ void xcd_remap(int& bx, int& by, int& bz) {
  int gx = gridDim.x, gy = gridDim.y;
  int nwg = gx * gy * gridDim.z;
  int hw = blockIdx.x + gx * (blockIdx.y + gy * blockIdx.z);
  int work = ((nwg & 7) == 0) ? ((hw & 7) * (nwg >> 3) + (hw >> 3)) : hw;
  bx = work % gx;
  int t = work / gx;
  by = t % gy;
  bz = t / gy;
}

// ---------------- fused weight transpose+cast for all 4 weights ------------
__global__ __launch_bounds__(256) void k_transpose_all(
    const float* __restrict__ wq, const float* __restrict__ wp,
    const float* __restrict__ w1, const float* __restrict__ w2,
    uint16_t* __restrict__ tq, uint16_t* __restrict__ tp,
    uint16_t* __restrict__ t1, uint16_t* __restrict__ t2) {
  __shared__ float tile[64][65];
  int id = blockIdx.x;
  const float* w; uint16_t* wT; int K, N, bx, by;
  if (id < 768)        { w = wq; wT = tq; K = 1024; N = 3072; bx = id % 48; by = id / 48; }
  else if (id < 1024)  { id -= 768;  w = wp; wT = tp; K = 1024; N = 1024; bx = id & 15; by = id >> 4; }
  else if (id < 2048)  { id -= 1024; w = w1; wT = t1; K = 1024; N = 4096; bx = id & 63; by = id >> 6; }
  else                 { id -= 2048; w = w2; wT = t2; K = 4096; N = 1024; bx = id & 15; by = id >> 4; }
  const int tx = threadIdx.x;
  const int k0 = by * 64, n0 = bx * 64;
  const int cr = tx & 15, rbase = tx >> 4;
#pragma unroll
  for (int rr = 0; rr < 4; ++rr) {
    int k = rbase + rr * 16;
    int n = cr * 4;
    float4 v = *(const float4*)&w[(size_t)(k0 + k) * N + (n0 + n)];
    tile[k][n + 0] = v.x; tile[k][n + 1] = v.y;
    tile[k][n + 2] = v.z; tile[k][n + 3] = v.w;
  }
  __syncthreads();
#pragma unroll
  for (int rr = 0; rr < 4; ++rr) {
    int n = rbase + rr * 16;
    int k = cr * 4;
    ushort4 o;
    o.x = f2b(tile[k + 0][n]);
    o.y = f2b(tile[k + 1][n]);
    o.z = f2b(tile[k + 2][n]);
    o.w = f2b(tile[k + 3][n]);
    *(ushort4*)&wT[(size_t)(n0 + n) * K + (k0 + k)] = o;
  }
}

// ---------------- layernorm: one wave per row of 1024, f32 in -> bf16 out --
__global__ __launch_bounds__(256) void k_layernorm(
    const float* __restrict__ x, const float* __restrict__ g,
    const float* __restrict__ b, uint16_t* __restrict__ out) {
  const int row = blockIdx.x * 4 + (threadIdx.x >> 6);
  const int lane = threadIdx.x & 63;
  const float* xr = x + (size_t)row * 1024;
  float4 v[4];
  float s = 0.f, ss = 0.f;
#pragma unroll
  for (int i = 0; i < 4; ++i) {
    v[i] = *(const float4*)&xr[i * 256 + lane * 4];
    s += v[i].x + v[i].y + v[i].z + v[i].w;
    ss += v[i].x * v[i].x + v[i].y * v[i].y + v[i].z * v[i].z + v[i].w * v[i].w;
  }
#pragma unroll
  for (int off = 1; off < 64; off <<= 1) {
    s += __shfl_xor(s, off);
    ss += __shfl_xor(ss, off);
  }
  float mu = s * (1.f / 1024.f);
  float rstd = rsqrtf(ss * (1.f / 1024.f) - mu * mu + 1e-5f);
#pragma unroll
  for (int i = 0; i < 4; ++i) {
    int col = i * 256 + lane * 4;
    float4 gv = *(const float4*)&g[col];
    float4 bv = *(const float4*)&b[col];
    ushort4 o;
    o.x = f2b((v[i].x - mu) * rstd * gv.x + bv.x);
    o.y = f2b((v[i].y - mu) * rstd * gv.y + bv.y);
    o.z = f2b((v[i].z - mu) * rstd * gv.z + bv.z);
    o.w = f2b((v[i].w - mu) * rstd * gv.w + bv.w);
    *(ushort4*)&out[(size_t)row * 1024 + col] = o;
  }
}

// ---------------- ln2 fuse: x2 = x + bias + pp0 + pp1; h = LN(x2)*g+b ------
__global__ __launch_bounds__(256) void k_ln2_fuse(
    const float* __restrict__ x, const uint16_t* __restrict__ pp0,
    const uint16_t* __restrict__ pp1, const float* __restrict__ bias,
    const float* __restrict__ g, const float* __restrict__ b,
    float* __restrict__ x2, uint16_t* __restrict__ out) {
  const int row = blockIdx.x * 4 + (threadIdx.x >> 6);
  const int lane = threadIdx.x & 63;
  const size_t rb = (size_t)row * 1024;
  float4 v[4];
  float s = 0.f, ss = 0.f;
#pragma unroll
  for (int i = 0; i < 4; ++i) {
    int col = i * 256 + lane * 4;
    float4 xv = *(const float4*)&x[rb + col];
    float4 bv = *(const float4*)&bias[col];
    ushort4 a0 = *(const ushort4*)&pp0[rb + col];
    ushort4 a1 = *(const ushort4*)&pp1[rb + col];
    v[i].x = xv.x + bv.x + b2f(a0.x) + b2f(a1.x);
    v[i].y = xv.y + bv.y + b2f(a0.y) + b2f(a1.y);
    v[i].z = xv.z + bv.z + b2f(a0.z) + b2f(a1.z);
    v[i].w = xv.w + bv.w + b2f(a0.w) + b2f(a1.w);
    *(float4*)&x2[rb + col] = v[i];
    s += v[i].x + v[i].y + v[i].z + v[i].w;
    ss += v[i].x * v[i].x + v[i].y * v[i].y + v[i].z * v[i].z + v[i].w * v[i].w;
  }
#pragma unroll
  for (int off = 1; off < 64; off <<= 1) {
    s += __shfl_xor(s, off);
    ss += __shfl_xor(ss, off);
  }
  float mu = s * (1.f / 1024.f);
  float rstd = rsqrtf(ss * (1.f / 1024.f) - mu * mu + 1e-5f);
#pragma unroll
  for (int i = 0; i < 4; ++i) {
    int col = i * 256 + lane * 4;
    float4 gv = *(const float4*)&g[col];
    float4 bv = *(const float4*)&b[col];
    ushort4 o;
    o.x = f2b((v[i].x - mu) * rstd * gv.x + bv.x);
    o.y = f2b((v[i].y - mu) * rstd * gv.y + bv.y);
    o.z = f2b((v[i].z - mu) * rstd * gv.z + bv.z);
    o.w = f2b((v[i].w - mu) * rstd * gv.w + bv.w);
    *(ushort4*)&out[rb + col] = o;
  }
}

// ---------------- fc2 reduce: out = x2 + bias + fp0 + fp1 ------------------
__global__ __launch_bounds__(256) void k_fc2_reduce(
    const float* __restrict__ x2, const uint16_t* __restrict__ f0,
    const uint16_t* __restrict__ f1, const float* __restrict__ bias,
    float* __restrict__ out, int N) {
  int i = (blockIdx.x * 256 + threadIdx.x) * 4;
  float4 v = *(const float4*)&x2[i];
  float4 bv = *(const float4*)&bias[i & (N - 1)];
  ushort4 a0 = *(const ushort4*)&f0[i];
  ushort4 a1 = *(const ushort4*)&f1[i];
  v.x += bv.x + b2f(a0.x) + b2f(a1.x);
  v.y += bv.y + b2f(a0.y) + b2f(a1.y);
  v.z += bv.z + b2f(a0.z) + b2f(a1.z);
  v.w += bv.w + b2f(a0.w) + b2f(a1.w);
  *(float4*)&out[i] = v;
}

// ---------------- GEMM: C[M,N] = A[M,K](bf16) @ Bt[N,K](bf16)^T + bias -----
// EPI 0: bf16 out. EPI 2: bf16 out, tanh-GELU. EPI 3: qkv (V cols -> vT).
template <int EPI>
__global__ __launch_bounds__(256) void k_gemm(
    const uint16_t* __restrict__ A, const uint16_t* __restrict__ Bt,
    const float* __restrict__ bias, void* __restrict__ Cout,
    uint16_t* __restrict__ vTout, int M, int N, int K) {
  __shared__ __align__(16) uint16_t Alds[128 * 64];
  __shared__ __align__(16) uint16_t Blds[128 * 64];
  int bx, by, bz;
  xcd_remap(bx, by, bz);
  const int tid = threadIdx.x;
  const int lane = tid & 63;
  const int w = tid >> 6;
  const int wr = w >> 1, wc = w & 1;
  const int m0 = by * 128, n0 = bx * 128;
  const int l15 = lane & 15, l4 = lane >> 4;
  const uint16_t* pA[4];
  const uint16_t* pB[4];
#pragma unroll
  for (int c = 0; c < 4; ++c) {
    int i = c * 256 + tid;
    int row = i >> 3, d = (i & 7) * 8;
    pA[c] = A + (size_t)(m0 + row) * K + d;
    pB[c] = Bt + (size_t)(n0 + row) * K + d;
  }
  f32x4 acc[4][4] = {};
  for (int k0 = 0; k0 < K; k0 += 64) {
#pragma unroll
    for (int c = 0; c < 4; ++c) {
      async16(&Alds[(c * 256 + tid) * 8], pA[c]);
      pA[c] += 64;
    }
#pragma unroll
    for (int c = 0; c < 4; ++c) {
      async16(&Blds[(c * 256 + tid) * 8], pB[c]);
      pB[c] += 64;
    }
    __syncthreads();
#pragma unroll
    for (int kc = 0; kc < 2; ++kc) {
      short8 af[4], bf[4];
#pragma unroll
      for (int m = 0; m < 4; ++m)
        af[m] = *(const short8*)&Alds[(wr * 64 + m * 16 + l15) * 64 + kc * 32 + l4 * 8];
#pragma unroll
      for (int n = 0; n < 4; ++n)
        bf[n] = *(const short8*)&Blds[(wc * 64 + n * 16 + l15) * 64 + kc * 32 + l4 * 8];
#pragma unroll
      for (int m = 0; m < 4; ++m)
#pragma unroll
        for (int n = 0; n < 4; ++n)
          acc[m][n] = __builtin_amdgcn_mfma_f32_16x16x32_bf16(af[m], bf[n], acc[m][n], 0, 0, 0);
    }
    __syncthreads();
  }
#pragma unroll
  for (int m = 0; m < 4; ++m) {
#pragma unroll
    for (int n = 0; n < 4; ++n) {
      int col = n0 + wc * 64 + n * 16 + l15;
      int rowb = m0 + wr * 64 + m * 16 + l4 * 4;
      float bv = bias[col];
      if constexpr (EPI == 3) {
        if (col >= 2048) {
          int dtot = col - 2048;
          int hh = dtot >> 6, dd = dtot & 63;
          int bg = rowb >> 11, tl = rowb & 2047;
          ushort4 ov;
          ov.x = f2b(acc[m][n][0] + bv);
          ov.y = f2b(acc[m][n][1] + bv);
          ov.z = f2b(acc[m][n][2] + bv);
          ov.w = f2b(acc[m][n][3] + bv);
          *(ushort4*)&vTout[(((size_t)(bg * 16 + hh)) * 64 + dd) * 2048 + tl] = ov;
          continue;
        }
      }
#pragma unroll
      for (int r = 0; r < 4; ++r) {
        float val = acc[m][n][r] + bv;
        size_t idx = (size_t)(rowb + r) * N + col;
        if constexpr (EPI == 2) {
          // tanh-form GELU via exp2
          float u = val * val;
          float a = fmaf(u, 0.1029480545f, 2.3022078158f);
          float t = exp2f(val * a);
          float gl = val - val / (t + 1.0f);
          ((uint16_t*)Cout)[idx] = f2b(gl);
        } else {
          ((uint16_t*)Cout)[idx] = f2b(val);
        }
      }
    }
  }
}

// ---------------- split-K GEMM: bf16 partial per k-slice (no atomics) ------
__global__ __launch_bounds__(256) void k_gemm_splitk(
    const uint16_t* __restrict__ A, const uint16_t* __restrict__ Bt,
    uint16_t* __restrict__ p0, uint16_t* __restrict__ p1,
    int M, int N, int K, int Kc) {
  __shared__ __align__(16) uint16_t Alds[128 * 64];
  __shared__ __align__(16) uint16_t Blds[128 * 64];
  int bx, by, bz;
  xcd_remap(bx, by, bz);
  const int tid = threadIdx.x;
  const int lane = tid & 63;
  const int w = tid >> 6;
  const int wr = w >> 1, wc = w & 1;
  const int m0 = by * 128, n0 = bx * 128;
  const int l15 = lane & 15, l4 = lane >> 4;
  const int kbeg = bz * Kc;
  uint16_t* __restrict__ P = (bz == 0) ? p0 : p1;
  const uint16_t* pA[4];
  const uint16_t* pB[4];
#pragma unroll
  for (int c = 0; c < 4; ++c) {
    int i = c * 256 + tid;
    int row = i >> 3, d = (i & 7) * 8;
    pA[c] = A + (size_t)(m0 + row) * K + kbeg + d;
    pB[c] = Bt + (size_t)(n0 + row) * K + kbeg + d;
  }
  f32x4 acc[4][4] = {};
  for (int k0 = 0; k0 < Kc; k0 += 64) {
#pragma unroll
    for (int c = 0; c < 4; ++c) {
      async16(&Alds[(c * 256 + tid) * 8], pA[c]);
      pA[c] += 64;
    }
#pragma unroll
    for (int c = 0; c < 4; ++c) {
      async16(&Blds[(c * 256 + tid) * 8], pB[c]);
      pB[c] += 64;
    }
    __syncthreads();
#pragma unroll
    for (int kc = 0; kc < 2; ++kc) {
      short8 af[4], bf[4];
#pragma unroll
      for (int m = 0; m < 4; ++m)
        af[m] = *(const short8*)&Alds[(wr * 64 + m * 16 + l15) * 64 + kc * 32 + l4 * 8];
#pragma unroll
      for (int n = 0; n < 4; ++n)
        bf[n] = *(const short8*)&Blds[(wc * 64 + n * 16 + l15) * 64 + kc * 32 + l4 * 8];
#pragma unroll
      for (int m = 0; m < 4; ++m)
#pragma unroll
        for (int n = 0; n < 4; ++n)
          acc[m][n] = __builtin_amdgcn_mfma_f32_16x16x32_bf16(af[m], bf[n], acc[m][n], 0, 0, 0);
    }
    __syncthreads();
  }
#pragma unroll
  for (int m = 0; m < 4; ++m) {
#pragma unroll
    for (int n = 0; n < 4; ++n) {
      int col = n0 + wc * 64 + n * 16 + l15;
      int rowb = m0 + wr * 64 + m * 16 + l4 * 4;
#pragma unroll
      for (int r = 0; r < 4; ++r)
        P[(size_t)(rowb + r) * N + col] = f2b(acc[m][n][r]);
    }
  }
}

// ---------------- flash attention v8: key-split 8-wave, 32 waves/CU --------
// v6 structure (LDS dbuf K/V via global_load_lds, swapped QK^T, ones-MFMA
// denominator, defer-max, setprio) with 512-thread blocks: waves 0-3 process
// keys [0,32) of every tile, waves 4-7 keys [32,64), same 64 q. Per-wave
// softmax/MFMA work halves; LDS stays 40KB -> 4 blocks/CU x 8 waves = 32
// waves/CU (2x v6 TLP). Key-group partials merged once at the end (standard
// flash merge; partials published through dead K/V LDS).
__global__ __launch_bounds__(512, 8) void k_attn(
    const uint16_t* __restrict__ qkv, const uint16_t* __restrict__ vT,
    uint16_t* __restrict__ ctx) {
  __shared__ __align__(16) uint16_t Klds[2][64 * 64];  // 16 KB
  __shared__ __align__(16) uint16_t Vlds[2][64 * 64];  // 16 KB
  __shared__ __align__(16) uint16_t Plds[8][16 * 32];  //  8 KB
  int bx, by, bz;
  xcd_remap(bx, by, bz);
  const int bh = by, qt = bx;
  const int b = bh >> 4, h = bh & 15;
  const int tid = threadIdx.x, lane = tid & 63, wv = tid >> 6;
  const int wq = wv & 3;        // q-tile within block
  const int g = wv >> 2;        // key group: 0 -> keys [0,32), 1 -> [32,64)
  const int l15 = lane & 15, l4 = lane >> 4;
  const int sw = (l15 & 7) << 3;
  const size_t tokbase = (size_t)b * 2048;

  // Q as B-fragment (col=q=l15, k=d), scaled by 0.125*log2e for exp2 domain
  const float QSC = 0.125f * 1.44269504088896340736f;
  short8 qa[2];
  const int qrow = qt * 64 + wq * 16 + l15;
#pragma unroll
  for (int kc = 0; kc < 2; ++kc) {
    short8 v = *(const short8*)&qkv[(tokbase + qrow) * 3072 + h * 64 + kc * 32 + l4 * 8];
#pragma unroll
    for (int j = 0; j < 8; ++j) v[j] = (short)f2b(b2f((uint16_t)v[j]) * QSC);
    qa[kc] = v;
  }
  short8 ones;
#pragma unroll
  for (int j = 0; j < 8; ++j) ones[j] = (short)0x3F80;

  float m_s = -1e30f;   // per-q running max (q = l15, replicated over l4)
  f32x4 o[4] = {};      // o[df][r]: q=l4*4+r, d=df*16+l15
  f32x4 ol = {};        // denominator partial, q=l4*4+r (replicated over l15)

  // staging: 512 threads, 1 K-load + 1 V-load each (64x64 bf16 tiles)
  const int srow = tid >> 3;
  const int scolS = ((tid & 7) * 8) ^ ((srow & 7) << 3);
  const uint16_t* pK = qkv + (tokbase + srow) * 3072 + 1024 + h * 64 + scolS;
  const uint16_t* pV = vT + ((size_t)bh * 64 + srow) * 2048 + scolS;

  auto stage = [&](int buf) {
    async16(&Klds[buf][tid * 8], pK);
    pK += 64 * 3072;
    async16(&Vlds[buf][tid * 8], pV);
    pV += 64;
  };

  stage(0);
  __syncthreads();
  int cur = 0;

  for (int t0 = 0; t0 < 2048; t0 += 64) {
    if (t0 + 64 < 2048) stage(cur ^ 1);

    // S^T = K @ Q^T for this wave's 32 keys (rows g*32 .. g*32+31)
    f32x4 s[2] = {};
    __builtin_amdgcn_s_setprio(1);
#pragma unroll
    for (int kc = 0; kc < 2; ++kc) {
      const int cc = (kc * 32 + l4 * 8) ^ sw;
#pragma unroll
      for (int c = 0; c < 2; ++c) {
        short8 kf = *(const short8*)&Klds[cur][(g * 32 + c * 16 + l15) * 64 + cc];
        s[c] = __builtin_amdgcn_mfma_f32_16x16x32_bf16(kf, qa[kc], s[c], 0, 0, 0);
      }
    }
    __builtin_amdgcn_s_setprio(0);

    // online softmax: lane owns q-row l15 (8 key-values in regs)
    {
      float a0 = fmaxf(fmaxf(s[0][0], s[0][1]), fmaxf(s[0][2], s[0][3]));
      float a1 = fmaxf(fmaxf(s[1][0], s[1][1]), fmaxf(s[1][2], s[1][3]));
      float pml = fmaxf(a0, a1);  // partial (lane) max
      if (!__all(pml - m_s <= 8.f)) {
        float pm = pml;
        pm = fmaxf(pm, __shfl_xor(pm, 16));
        pm = fmaxf(pm, __shfl_xor(pm, 32));    // row max for q=l15
        float mn = fmaxf(m_s, pm);
        float scale = exp2f(m_s - mn);
        m_s = mn;
        float sc0 = __shfl(scale, l4 * 4 + 0);
        float sc1 = __shfl(scale, l4 * 4 + 1);
        float sc2 = __shfl(scale, l4 * 4 + 2);
        float sc3 = __shfl(scale, l4 * 4 + 3);
#pragma unroll
        for (int df = 0; df < 4; ++df) {
          o[df][0] *= sc0; o[df][1] *= sc1; o[df][2] *= sc2; o[df][3] *= sc3;
        }
        ol[0] *= sc0; ol[1] *= sc1; ol[2] *= sc2; ol[3] *= sc3;
      }
#pragma unroll
      for (int c = 0; c < 2; ++c) {
        float p0 = exp2f(s[c][0] - m_s);
        float p1 = exp2f(s[c][1] - m_s);
        float p2 = exp2f(s[c][2] - m_s);
        float p3 = exp2f(s[c][3] - m_s);
        uint32_t lo, hi;
        asm("v_cvt_pk_bf16_f32 %0, %1, %2" : "=v"(lo) : "v"(p0), "v"(p1));
        asm("v_cvt_pk_bf16_f32 %0, %1, %2" : "=v"(hi) : "v"(p2), "v"(p3));
        // P[q=l15][key_local=c*16+l4*4 .. +3], linear 32-col tile
        *(uint2*)&Plds[wv][l15 * 32 + c * 16 + l4 * 4] = make_uint2(lo, hi);
      }
    }

    // O += P @ V over this wave's 32 keys (single k=32 fragment)
    __builtin_amdgcn_s_setprio(1);
    {
      short8 pa = *(const short8*)&Plds[wv][l15 * 32 + l4 * 8];
      ol = __builtin_amdgcn_mfma_f32_16x16x32_bf16(pa, ones, ol, 0, 0, 0);
      const int cc = (g * 32 + l4 * 8) ^ sw;
#pragma unroll
      for (int df = 0; df < 4; ++df) {
        short8 vf = *(const short8*)&Vlds[cur][(df * 16 + l15) * 64 + cc];
        o[df] = __builtin_amdgcn_mfma_f32_16x16x32_bf16(pa, vf, o[df], 0, 0, 0);
      }
    }
    __builtin_amdgcn_s_setprio(0);
    __syncthreads();
    cur ^= 1;
  }

  // ---- merge the two key-group partials (overlay dead Klds/Vlds) ----
  float* oB  = (float*)&Klds[0][0];   // [16][256]: (df*4+r)*256 + wq*64 + lane
  float* olB = (float*)&Vlds[0][0];   // [4][256]:  r*256 + wq*64 + lane
  float* mB  = olB + 1024;            // [256]: wq*64 + lane
  if (g == 1) {
#pragma unroll
    for (int df = 0; df < 4; ++df)
#pragma unroll
      for (int r = 0; r < 4; ++r)
        oB[(df * 4 + r) * 256 + wq * 64 + lane] = o[df][r];
#pragma unroll
    for (int r = 0; r < 4; ++r)
      olB[r * 256 + wq * 64 + lane] = ol[r];
    mB[wq * 64 + lane] = m_s;
  }
  __syncthreads();
  if (g == 0) {
    // merged scale per q (computed at lane with l15=q, distributed via shfl)
    float mBq = mB[wq * 64 + lane];          // partner's m for q=l15
    float mq = fmaxf(m_s, mBq);
    float sAq = exp2f(m_s - mq);
    float sBq = exp2f(mBq - mq);
    float sA[4], sB[4];
#pragma unroll
    for (int r = 0; r < 4; ++r) {
      sA[r] = __shfl(sAq, l4 * 4 + r);
      sB[r] = __shfl(sBq, l4 * 4 + r);
    }
#pragma unroll
    for (int r = 0; r < 4; ++r) {
      float lT = ol[r] * sA[r] + olB[r * 256 + wq * 64 + lane] * sB[r];
      float rl = 1.0f / lT;
      int tok = qt * 64 + wq * 16 + l4 * 4 + r;
#pragma unroll
      for (int df = 0; df < 4; ++df) {
        float val = o[df][r] * sA[r] + oB[(df * 4 + r) * 256 + wq * 64 + lane] * sB[r];
        ctx[(tokbase + tok) * 1024 + h * 64 + df * 16 + l15] = f2b(val * rl);
      }
    }
  }
}

// ---------------------------------------------------------------------------
extern "C" void kernel_launch(void* const* d_in, const int* in_sizes, int n_in,
                              void* d_out, int out_size, void* d_ws, size_t ws_size,
                              hipStream_t stream) {
  const float* x      = (const float*)d_in[0];
  const float* ln1_g  = (const float*)d_in[1];
  const float* ln1_b  = (const float*)d_in[2];
  const float* ln2_g  = (const float*)d_in[3];
  const float* ln2_b  = (const float*)d_in[4];
  const float* w_qkv  = (const float*)d_in[5];
  const float* b_qkv  = (const float*)d_in[6];
  const float* w_proj = (const float*)d_in[7];
  const float* b_proj = (const float*)d_in[8];
  const float* w_fc1  = (const float*)d_in[9];
  const float* b_fc1  = (const float*)d_in[10];
  const float* w_fc2  = (const float*)d_in[11];
  const float* b_fc2  = (const float*)d_in[12];
  float* out = (float*)d_out;
  char* ws = (char*)d_ws;
  const size_t MB = 1 << 20;

  // workspace layout (MB offsets), peak 88 MB; aliasing by liveness:
  uint16_t* wTfc1  = (uint16_t*)(ws + 0 * MB);    //  8 MB, dead after fc1
  uint16_t* wTfc2  = (uint16_t*)(ws + 8 * MB);    //  8 MB, live to fc2
  uint16_t* wTqkv  = (uint16_t*)(ws + 16 * MB);   //  6 MB, dead after qkv
  uint16_t* wTproj = (uint16_t*)(ws + 22 * MB);   //  2 MB, dead after proj
  uint16_t* hbuf   = (uint16_t*)(ws + 24 * MB);   //  8 MB, dead after fc1
  uint16_t* qkvb   = (uint16_t*)(ws + 32 * MB);   // 24 MB, dead after attn
  uint16_t* vTb    = (uint16_t*)(ws + 56 * MB);   //  8 MB, dead after attn
  uint16_t* ctxb   = (uint16_t*)(ws + 64 * MB);   //  8 MB, dead after proj
  float*    x2b    = (float*)   (ws + 72 * MB);   // 16 MB, live to reduce
  uint16_t* pp0    = (uint16_t*)(ws + 32 * MB);   //  8 MB proj partial (alias qkvb)
  uint16_t* pp1    = (uint16_t*)(ws + 40 * MB);   //  8 MB proj partial
  uint16_t* actb   = (uint16_t*)(ws + 32 * MB);   // 32 MB fc1 out (alias qkvb/vTb)
  uint16_t* fp0    = (uint16_t*)(ws + 16 * MB);   //  8 MB fc2 partial (alias wTqkv/proj)
  uint16_t* fp1    = (uint16_t*)(ws + 24 * MB);   //  8 MB fc2 partial (alias hbuf)

  k_transpose_all<<<3072, 256, 0, stream>>>(w_qkv, w_proj, w_fc1, w_fc2,
                                            wTqkv, wTproj, wTfc1, wTfc2);

  k_layernorm<<<1024, 256, 0, stream>>>(x, ln1_g, ln1_b, hbuf);
  // qkv GEMM: Q/K cols -> qkvb, V cols -> vTb (transposed in-epilogue)
  k_gemm<3><<<dim3(24, 32), 256, 0, stream>>>(hbuf, wTqkv, b_qkv, qkvb, vTb, 4096, 3072, 1024);
  k_attn<<<dim3(32, 32), 512, 0, stream>>>(qkvb, vTb, ctxb);

  // proj: partials (split-K=2), reduced inside ln2_fuse
  k_gemm_splitk<<<dim3(8, 32, 2), 256, 0, stream>>>(ctxb, wTproj, pp0, pp1,
                                                    4096, 1024, 1024, 512);
  k_ln2_fuse<<<1024, 256, 0, stream>>>(x, pp0, pp1, b_proj, ln2_g, ln2_b, x2b, hbuf);

  k_gemm<2><<<dim3(32, 32), 256, 0, stream>>>(hbuf, wTfc1, b_fc1, actb, nullptr, 4096, 4096, 1024);

  // fc2: partials (split-K=2, Kc=2048), reduced with residual+bias into out
  k_gemm_splitk<<<dim3(8, 32, 2), 256, 0, stream>>>(actb, wTfc2, fp0, fp1,
                                                    4096, 1024, 4096, 2048);
  k_fc2_reduce<<<4096, 256, 0, stream>>>(x2b, fp0, fp1, b_fc2, out, 1024);
}

// Round 13
// 296.006 us; speedup vs baseline: 1.0265x; 1.0265x over previous
//
#include <hip/hip_runtime.h>
#include <hip/hip_bf16.h>
#include <cstdint>

typedef __attribute__((ext_vector_type(8))) short short8;
typedef __attribute__((ext_vector_type(4))) float f32x4;

__device__ __forceinline__ uint16_t f2b(float f) {
  uint32_t u = __builtin_bit_cast(uint32_t, f);
  return (uint16_t)((u + 0x7FFFu + ((u >> 16) & 1u)) >> 16);
}
__device__ __forceinline__ float b2f(uint16_t h) {
  uint32_t u = ((uint32_t)h) << 16;
  return __builtin_bit_cast(float, u);
}
// async global->LDS, 16B per lane. LDS dest must be wave-uniform base + lane*16.
__device__ __forceinline__ void async16(void* lds, const void* g) {
  __builtin_amdgcn_global_load_lds(
      (const __attribute__((address_space(1))) uint32_t*)g,
      (__attribute__((address_space(3))) uint32_t*)lds, 16, 0, 0);
}
// T1: XCD-chunked bijective remap (nwg % 8 == 0 for all our MFMA grids).
__device__ __forceinline__ void xcd_remap(int& bx, int& by, int& bz) {
  int gx = gridDim.x, gy = gridDim.y;
  int nwg = gx * gy * gridDim.z;
  int hw = blockIdx.x + gx * (blockIdx.y + gy * blockIdx.z);
  int work = ((nwg & 7) == 0) ? ((hw & 7) * (nwg >> 3) + (hw >> 3)) : hw;
  bx = work % gx;
  int t = work / gx;
  by = t % gy;
  bz = t / gy;
}

// ---------------- fused weight transpose+cast for all 4 weights ------------
__global__ __launch_bounds__(256) void k_transpose_all(
    const float* __restrict__ wq, const float* __restrict__ wp,
    const float* __restrict__ w1, const float* __restrict__ w2,
    uint16_t* __restrict__ tq, uint16_t* __restrict__ tp,
    uint16_t* __restrict__ t1, uint16_t* __restrict__ t2) {
  __shared__ float tile[64][65];
  int id = blockIdx.x;
  const float* w; uint16_t* wT; int K, N, bx, by;
  if (id < 768)        { w = wq; wT = tq; K = 1024; N = 3072; bx = id % 48; by = id / 48; }
  else if (id < 1024)  { id -= 768;  w = wp; wT = tp; K = 1024; N = 1024; bx = id & 15; by = id >> 4; }
  else if (id < 2048)  { id -= 1024; w = w1; wT = t1; K = 1024; N = 4096; bx = id & 63; by = id >> 6; }
  else                 { id -= 2048; w = w2; wT = t2; K = 4096; N = 1024; bx = id & 15; by = id >> 4; }
  const int tx = threadIdx.x;
  const int k0 = by * 64, n0 = bx * 64;
  const int cr = tx & 15, rbase = tx >> 4;
#pragma unroll
  for (int rr = 0; rr < 4; ++rr) {
    int k = rbase + rr * 16;
    int n = cr * 4;
    float4 v = *(const float4*)&w[(size_t)(k0 + k) * N + (n0 + n)];
    tile[k][n + 0] = v.x; tile[k][n + 1] = v.y;
    tile[k][n + 2] = v.z; tile[k][n + 3] = v.w;
  }
  __syncthreads();
#pragma unroll
  for (int rr = 0; rr < 4; ++rr) {
    int n = rbase + rr * 16;
    int k = cr * 4;
    ushort4 o;
    o.x = f2b(tile[k + 0][n]);
    o.y = f2b(tile[k + 1][n]);
    o.z = f2b(tile[k + 2][n]);
    o.w = f2b(tile[k + 3][n]);
    *(ushort4*)&wT[(size_t)(n0 + n) * K + (k0 + k)] = o;
  }
}

// ---------------- layernorm: one wave per row of 1024, f32 in -> bf16 out --
__global__ __launch_bounds__(256) void k_layernorm(
    const float* __restrict__ x, const float* __restrict__ g,
    const float* __restrict__ b, uint16_t* __restrict__ out) {
  const int row = blockIdx.x * 4 + (threadIdx.x >> 6);
  const int lane = threadIdx.x & 63;
  const float* xr = x + (size_t)row * 1024;
  float4 v[4];
  float s = 0.f, ss = 0.f;
#pragma unroll
  for (int i = 0; i < 4; ++i) {
    v[i] = *(const float4*)&xr[i * 256 + lane * 4];
    s += v[i].x + v[i].y + v[i].z + v[i].w;
    ss += v[i].x * v[i].x + v[i].y * v[i].y + v[i].z * v[i].z + v[i].w * v[i].w;
  }
#pragma unroll
  for (int off = 1; off < 64; off <<= 1) {
    s += __shfl_xor(s, off);
    ss += __shfl_xor(ss, off);
  }
  float mu = s * (1.f / 1024.f);
  float rstd = rsqrtf(ss * (1.f / 1024.f) - mu * mu + 1e-5f);
#pragma unroll
  for (int i = 0; i < 4; ++i) {
    int col = i * 256 + lane * 4;
    float4 gv = *(const float4*)&g[col];
    float4 bv = *(const float4*)&b[col];
    ushort4 o;
    o.x = f2b((v[i].x - mu) * rstd * gv.x + bv.x);
    o.y = f2b((v[i].y - mu) * rstd * gv.y + bv.y);
    o.z = f2b((v[i].z - mu) * rstd * gv.z + bv.z);
    o.w = f2b((v[i].w - mu) * rstd * gv.w + bv.w);
    *(ushort4*)&out[(size_t)row * 1024 + col] = o;
  }
}

// ---------------- ln2 fuse: x2 = x + bias + pp0 + pp1; h = LN(x2)*g+b ------
__global__ __launch_bounds__(256) void k_ln2_fuse(
    const float* __restrict__ x, const uint16_t* __restrict__ pp0,
    const uint16_t* __restrict__ pp1, const float* __restrict__ bias,
    const float* __restrict__ g, const float* __restrict__ b,
    float* __restrict__ x2, uint16_t* __restrict__ out) {
  const int row = blockIdx.x * 4 + (threadIdx.x >> 6);
  const int lane = threadIdx.x & 63;
  const size_t rb = (size_t)row * 1024;
  float4 v[4];
  float s = 0.f, ss = 0.f;
#pragma unroll
  for (int i = 0; i < 4; ++i) {
    int col = i * 256 + lane * 4;
    float4 xv = *(const float4*)&x[rb + col];
    float4 bv = *(const float4*)&bias[col];
    ushort4 a0 = *(const ushort4*)&pp0[rb + col];
    ushort4 a1 = *(const ushort4*)&pp1[rb + col];
    v[i].x = xv.x + bv.x + b2f(a0.x) + b2f(a1.x);
    v[i].y = xv.y + bv.y + b2f(a0.y) + b2f(a1.y);
    v[i].z = xv.z + bv.z + b2f(a0.z) + b2f(a1.z);
    v[i].w = xv.w + bv.w + b2f(a0.w) + b2f(a1.w);
    *(float4*)&x2[rb + col] = v[i];
    s += v[i].x + v[i].y + v[i].z + v[i].w;
    ss += v[i].x * v[i].x + v[i].y * v[i].y + v[i].z * v[i].z + v[i].w * v[i].w;
  }
#pragma unroll
  for (int off = 1; off < 64; off <<= 1) {
    s += __shfl_xor(s, off);
    ss += __shfl_xor(ss, off);
  }
  float mu = s * (1.f / 1024.f);
  float rstd = rsqrtf(ss * (1.f / 1024.f) - mu * mu + 1e-5f);
#pragma unroll
  for (int i = 0; i < 4; ++i) {
    int col = i * 256 + lane * 4;
    float4 gv = *(const float4*)&g[col];
    float4 bv = *(const float4*)&b[col];
    ushort4 o;
    o.x = f2b((v[i].x - mu) * rstd * gv.x + bv.x);
    o.y = f2b((v[i].y - mu) * rstd * gv.y + bv.y);
    o.z = f2b((v[i].z - mu) * rstd * gv.z + bv.z);
    o.w = f2b((v[i].w - mu) * rstd * gv.w + bv.w);
    *(ushort4*)&out[rb + col] = o;
  }
}

// ---------------- fc2 reduce: out = x2 + bias + fp0 + fp1 ------------------
__global__ __launch_bounds__(256) void k_fc2_reduce(
    const float* __restrict__ x2, const uint16_t* __restrict__ f0,
    const uint16_t* __restrict__ f1, const float* __restrict__ bias,
    float* __restrict__ out, int N) {
  int i = (blockIdx.x * 256 + threadIdx.x) * 4;
  float4 v = *(const float4*)&x2[i];
  float4 bv = *(const float4*)&bias[i & (N - 1)];
  ushort4 a0 = *(const ushort4*)&f0[i];
  ushort4 a1 = *(const ushort4*)&f1[i];
  v.x += bv.x + b2f(a0.x) + b2f(a1.x);
  v.y += bv.y + b2f(a0.y) + b2f(a1.y);
  v.z += bv.z + b2f(a0.z) + b2f(a1.z);
  v.w += bv.w + b2f(a0.w) + b2f(a1.w);
  *(float4*)&out[i] = v;
}

// ---------------- GEMM: C[M,N] = A[M,K](bf16) @ Bt[N,K](bf16)^T + bias -----
// EPI 0: bf16 out. EPI 2: bf16 out, tanh-GELU. EPI 3: qkv (V cols -> vT).
template <int EPI>
__global__ __launch_bounds__(256) void k_gemm(
    const uint16_t* __restrict__ A, const uint16_t* __restrict__ Bt,
    const float* __restrict__ bias, void* __restrict__ Cout,
    uint16_t* __restrict__ vTout, int M, int N, int K) {
  __shared__ __align__(16) uint16_t Alds[128 * 64];
  __shared__ __align__(16) uint16_t Blds[128 * 64];
  int bx, by, bz;
  xcd_remap(bx, by, bz);
  const int tid = threadIdx.x;
  const int lane = tid & 63;
  const int w = tid >> 6;
  const int wr = w >> 1, wc = w & 1;
  const int m0 = by * 128, n0 = bx * 128;
  const int l15 = lane & 15, l4 = lane >> 4;
  const uint16_t* pA[4];
  const uint16_t* pB[4];
#pragma unroll
  for (int c = 0; c < 4; ++c) {
    int i = c * 256 + tid;
    int row = i >> 3, d = (i & 7) * 8;
    pA[c] = A + (size_t)(m0 + row) * K + d;
    pB[c] = Bt + (size_t)(n0 + row) * K + d;
  }
  f32x4 acc[4][4] = {};
  for (int k0 = 0; k0 < K; k0 += 64) {
#pragma unroll
    for (int c = 0; c < 4; ++c) {
      async16(&Alds[(c * 256 + tid) * 8], pA[c]);
      pA[c] += 64;
    }
#pragma unroll
    for (int c = 0; c < 4; ++c) {
      async16(&Blds[(c * 256 + tid) * 8], pB[c]);
      pB[c] += 64;
    }
    __syncthreads();
#pragma unroll
    for (int kc = 0; kc < 2; ++kc) {
      short8 af[4], bf[4];
#pragma unroll
      for (int m = 0; m < 4; ++m)
        af[m] = *(const short8*)&Alds[(wr * 64 + m * 16 + l15) * 64 + kc * 32 + l4 * 8];
#pragma unroll
      for (int n = 0; n < 4; ++n)
        bf[n] = *(const short8*)&Blds[(wc * 64 + n * 16 + l15) * 64 + kc * 32 + l4 * 8];
#pragma unroll
      for (int m = 0; m < 4; ++m)
#pragma unroll
        for (int n = 0; n < 4; ++n)
          acc[m][n] = __builtin_amdgcn_mfma_f32_16x16x32_bf16(af[m], bf[n], acc[m][n], 0, 0, 0);
    }
    __syncthreads();
  }
#pragma unroll
  for (int m = 0; m < 4; ++m) {
#pragma unroll
    for (int n = 0; n < 4; ++n) {
      int col = n0 + wc * 64 + n * 16 + l15;
      int rowb = m0 + wr * 64 + m * 16 + l4 * 4;
      float bv = bias[col];
      if constexpr (EPI == 3) {
        if (col >= 2048) {
          int dtot = col - 2048;
          int hh = dtot >> 6, dd = dtot & 63;
          int bg = rowb >> 11, tl = rowb & 2047;
          ushort4 ov;
          ov.x = f2b(acc[m][n][0] + bv);
          ov.y = f2b(acc[m][n][1] + bv);
          ov.z = f2b(acc[m][n][2] + bv);
          ov.w = f2b(acc[m][n][3] + bv);
          *(ushort4*)&vTout[(((size_t)(bg * 16 + hh)) * 64 + dd) * 2048 + tl] = ov;
          continue;
        }
      }
#pragma unroll
      for (int r = 0; r < 4; ++r) {
        float val = acc[m][n][r] + bv;
        size_t idx = (size_t)(rowb + r) * N + col;
        if constexpr (EPI == 2) {
          // tanh-form GELU via exp2
          float u = val * val;
          float a = fmaf(u, 0.1029480545f, 2.3022078158f);
          float t = exp2f(val * a);
          float gl = val - val / (t + 1.0f);
          ((uint16_t*)Cout)[idx] = f2b(gl);
        } else {
          ((uint16_t*)Cout)[idx] = f2b(val);
        }
      }
    }
  }
}

// ---------------- split-K GEMM: bf16 partial per k-slice (no atomics) ------
__global__ __launch_bounds__(256) void k_gemm_splitk(
    const uint16_t* __restrict__ A, const uint16_t* __restrict__ Bt,
    uint16_t* __restrict__ p0, uint16_t* __restrict__ p1,
    int M, int N, int K, int Kc) {
  __shared__ __align__(16) uint16_t Alds[128 * 64];
  __shared__ __align__(16) uint16_t Blds[128 * 64];
  int bx, by, bz;
  xcd_remap(bx, by, bz);
  const int tid = threadIdx.x;
  const int lane = tid & 63;
  const int w = tid >> 6;
  const int wr = w >> 1, wc = w & 1;
  const int m0 = by * 128, n0 = bx * 128;
  const int l15 = lane & 15, l4 = lane >> 4;
  const int kbeg = bz * Kc;
  uint16_t* __restrict__ P = (bz == 0) ? p0 : p1;
  const uint16_t* pA[4];
  const uint16_t* pB[4];
#pragma unroll
  for (int c = 0; c < 4; ++c) {
    int i = c * 256 + tid;
    int row = i >> 3, d = (i & 7) * 8;
    pA[c] = A + (size_t)(m0 + row) * K + kbeg + d;
    pB[c] = Bt + (size_t)(n0 + row) * K + kbeg + d;
  }
  f32x4 acc[4][4] = {};
  for (int k0 = 0; k0 < Kc; k0 += 64) {
#pragma unroll
    for (int c = 0; c < 4; ++c) {
      async16(&Alds[(c * 256 + tid) * 8], pA[c]);
      pA[c] += 64;
    }
#pragma unroll
    for (int c = 0; c < 4; ++c) {
      async16(&Blds[(c * 256 + tid) * 8], pB[c]);
      pB[c] += 64;
    }
    __syncthreads();
#pragma unroll
    for (int kc = 0; kc < 2; ++kc) {
      short8 af[4], bf[4];
#pragma unroll
      for (int m = 0; m < 4; ++m)
        af[m] = *(const short8*)&Alds[(wr * 64 + m * 16 + l15) * 64 + kc * 32 + l4 * 8];
#pragma unroll
      for (int n = 0; n < 4; ++n)
        bf[n] = *(const short8*)&Blds[(wc * 64 + n * 16 + l15) * 64 + kc * 32 + l4 * 8];
#pragma unroll
      for (int m = 0; m < 4; ++m)
#pragma unroll
        for (int n = 0; n < 4; ++n)
          acc[m][n] = __builtin_amdgcn_mfma_f32_16x16x32_bf16(af[m], bf[n], acc[m][n], 0, 0, 0);
    }
    __syncthreads();
  }
#pragma unroll
  for (int m = 0; m < 4; ++m) {
#pragma unroll
    for (int n = 0; n < 4; ++n) {
      int col = n0 + wc * 64 + n * 16 + l15;
      int rowb = m0 + wr * 64 + m * 16 + l4 * 4;
#pragma unroll
      for (int r = 0; r < 4; ++r)
        P[(size_t)(rowb + r) * N + col] = f2b(acc[m][n][r]);
    }
  }
}

// ---------------- flash attention v9: key-split 8-wave + in-register P -----
// v8 structure (keys split across wave groups g=0/1, flash-merge at end)
// but P never touches LDS: after cvt_pk, the PV A-fragment is built by a
// 3-bit rotation (reg-bit c <-> lane5 <-> lane4) via 2x v_permlane32_swap
// + 2x v_permlane16_swap (gfx950 MFMA-layout-swap instructions; permlane32
// form HW-validated in v7). Removes all P bank conflicts (v8's 15.7M) and
// 8KB LDS -> 32KB total, 4 blocks/CU x 8 waves = 32 waves/CU.
__global__ __launch_bounds__(512, 8) void k_attn(
    const uint16_t* __restrict__ qkv, const uint16_t* __restrict__ vT,
    uint16_t* __restrict__ ctx) {
  __shared__ __align__(16) uint16_t Klds[2][64 * 64];  // 16 KB
  __shared__ __align__(16) uint16_t Vlds[2][64 * 64];  // 16 KB
  int bx, by, bz;
  xcd_remap(bx, by, bz);
  const int bh = by, qt = bx;
  const int b = bh >> 4, h = bh & 15;
  const int tid = threadIdx.x, lane = tid & 63, wv = tid >> 6;
  const int wq = wv & 3;        // q-tile within block
  const int g = wv >> 2;        // key group: 0 -> keys [0,32), 1 -> [32,64)
  const int l15 = lane & 15, l4 = lane >> 4;
  const int sw = (l15 & 7) << 3;
  const size_t tokbase = (size_t)b * 2048;

  // Q as B-fragment (col=q=l15, k=d), scaled by 0.125*log2e for exp2 domain
  const float QSC = 0.125f * 1.44269504088896340736f;
  short8 qa[2];
  const int qrow = qt * 64 + wq * 16 + l15;
#pragma unroll
  for (int kc = 0; kc < 2; ++kc) {
    short8 v = *(const short8*)&qkv[(tokbase + qrow) * 3072 + h * 64 + kc * 32 + l4 * 8];
#pragma unroll
    for (int j = 0; j < 8; ++j) v[j] = (short)f2b(b2f((uint16_t)v[j]) * QSC);
    qa[kc] = v;
  }
  short8 ones;
#pragma unroll
  for (int j = 0; j < 8; ++j) ones[j] = (short)0x3F80;

  float m_s = -1e30f;   // per-q running max (q = l15, replicated over l4)
  f32x4 o[4] = {};      // o[df][r]: q=l4*4+r, d=df*16+l15
  f32x4 ol = {};        // denominator partial, q=l4*4+r (replicated over l15)

  // staging: 512 threads, 1 K-load + 1 V-load each (64x64 bf16 tiles)
  const int srow = tid >> 3;
  const int scolS = ((tid & 7) * 8) ^ ((srow & 7) << 3);
  const uint16_t* pK = qkv + (tokbase + srow) * 3072 + 1024 + h * 64 + scolS;
  const uint16_t* pV = vT + ((size_t)bh * 64 + srow) * 2048 + scolS;

  auto stage = [&](int buf) {
    async16(&Klds[buf][tid * 8], pK);
    pK += 64 * 3072;
    async16(&Vlds[buf][tid * 8], pV);
    pV += 64;
  };

  stage(0);
  __syncthreads();
  int cur = 0;

  for (int t0 = 0; t0 < 2048; t0 += 64) {
    if (t0 + 64 < 2048) stage(cur ^ 1);

    // S^T = K @ Q^T for this wave's 32 keys (rows g*32 .. g*32+31)
    f32x4 s[2] = {};
    __builtin_amdgcn_s_setprio(1);
#pragma unroll
    for (int kc = 0; kc < 2; ++kc) {
      const int cc = (kc * 32 + l4 * 8) ^ sw;
#pragma unroll
      for (int c = 0; c < 2; ++c) {
        short8 kf = *(const short8*)&Klds[cur][(g * 32 + c * 16 + l15) * 64 + cc];
        s[c] = __builtin_amdgcn_mfma_f32_16x16x32_bf16(kf, qa[kc], s[c], 0, 0, 0);
      }
    }
    __builtin_amdgcn_s_setprio(0);

    // online softmax: lane owns q-row l15 (8 key-values in regs)
    float pml;
    {
      float a0 = fmaxf(fmaxf(s[0][0], s[0][1]), fmaxf(s[0][2], s[0][3]));
      float a1 = fmaxf(fmaxf(s[1][0], s[1][1]), fmaxf(s[1][2], s[1][3]));
      pml = fmaxf(a0, a1);  // partial (lane) max
      if (!__all(pml - m_s <= 8.f)) {
        float pm = pml;
        pm = fmaxf(pm, __shfl_xor(pm, 16));
        pm = fmaxf(pm, __shfl_xor(pm, 32));    // row max for q=l15
        float mn = fmaxf(m_s, pm);
        float scale = exp2f(m_s - mn);
        m_s = mn;
        float sc0 = __shfl(scale, l4 * 4 + 0);
        float sc1 = __shfl(scale, l4 * 4 + 1);
        float sc2 = __shfl(scale, l4 * 4 + 2);
        float sc3 = __shfl(scale, l4 * 4 + 3);
#pragma unroll
        for (int df = 0; df < 4; ++df) {
          o[df][0] *= sc0; o[df][1] *= sc1; o[df][2] *= sc2; o[df][3] *= sc3;
        }
        ol[0] *= sc0; ol[1] *= sc1; ol[2] *= sc2; ol[3] *= sc3;
      }
    }

    // exp2 + pack; pk[c*2+i] = bf16pair{P[q=l15][c*16+l4*4+2i], ..+2i+1}
    uint32_t pk[4];
#pragma unroll
    for (int c = 0; c < 2; ++c) {
      float p0 = exp2f(s[c][0] - m_s);
      float p1 = exp2f(s[c][1] - m_s);
      float p2 = exp2f(s[c][2] - m_s);
      float p3 = exp2f(s[c][3] - m_s);
      asm("v_cvt_pk_bf16_f32 %0, %1, %2" : "=v"(pk[c * 2 + 0]) : "v"(p0), "v"(p1));
      asm("v_cvt_pk_bf16_f32 %0, %1, %2" : "=v"(pk[c * 2 + 1]) : "v"(p2), "v"(p3));
    }
    // build PV A-fragment in registers: rotate (reg-bit c, lane5, lane4).
    // step 1: swap reg-bit <-> lane5 ; step 2: swap reg-bit <-> lane4.
    uint32_t A0 = pk[0], A1 = pk[1], B0 = pk[2], B1 = pk[3];
    asm("v_permlane32_swap_b32 %0, %1" : "+v"(A0), "+v"(B0));
    asm("v_permlane32_swap_b32 %0, %1" : "+v"(A1), "+v"(B1));
    asm("v_permlane16_swap_b32 %0, %1" : "+v"(A0), "+v"(B0));
    asm("v_permlane16_swap_b32 %0, %1" : "+v"(A1), "+v"(B1));
    short8 pa = __builtin_bit_cast(short8, make_uint4(A0, A1, B0, B1));

    // O += P @ V over this wave's 32 keys (single k=32 fragment)
    __builtin_amdgcn_s_setprio(1);
    {
      ol = __builtin_amdgcn_mfma_f32_16x16x32_bf16(pa, ones, ol, 0, 0, 0);
      const int cc = (g * 32 + l4 * 8) ^ sw;
#pragma unroll
      for (int df = 0; df < 4; ++df) {
        short8 vf = *(const short8*)&Vlds[cur][(df * 16 + l15) * 64 + cc];
        o[df] = __builtin_amdgcn_mfma_f32_16x16x32_bf16(pa, vf, o[df], 0, 0, 0);
      }
    }
    __builtin_amdgcn_s_setprio(0);
    __syncthreads();
    cur ^= 1;
  }

  // ---- merge the two key-group partials (overlay dead Klds/Vlds) ----
  float* oB  = (float*)&Klds[0][0];   // [16][256]: (df*4+r)*256 + wq*64 + lane
  float* olB = (float*)&Vlds[0][0];   // [4][256]:  r*256 + wq*64 + lane
  float* mB  = olB + 1024;            // [256]: wq*64 + lane
  if (g == 1) {
#pragma unroll
    for (int df = 0; df < 4; ++df)
#pragma unroll
      for (int r = 0; r < 4; ++r)
        oB[(df * 4 + r) * 256 + wq * 64 + lane] = o[df][r];
#pragma unroll
    for (int r = 0; r < 4; ++r)
      olB[r * 256 + wq * 64 + lane] = ol[r];
    mB[wq * 64 + lane] = m_s;
  }
  __syncthreads();
  if (g == 0) {
    // merged scale per q (computed at lane with l15=q, distributed via shfl)
    float mBq = mB[wq * 64 + lane];          // partner's m for q=l15
    float mq = fmaxf(m_s, mBq);
    float sAq = exp2f(m_s - mq);
    float sBq = exp2f(mBq - mq);
    float sA[4], sB[4];
#pragma unroll
    for (int r = 0; r < 4; ++r) {
      sA[r] = __shfl(sAq, l4 * 4 + r);
      sB[r] = __shfl(sBq, l4 * 4 + r);
    }
#pragma unroll
    for (int r = 0; r < 4; ++r) {
      float lT = ol[r] * sA[r] + olB[r * 256 + wq * 64 + lane] * sB[r];
      float rl = 1.0f / lT;
      int tok = qt * 64 + wq * 16 + l4 * 4 + r;
#pragma unroll
      for (int df = 0; df < 4; ++df) {
        float val = o[df][r] * sA[r] + oB[(df * 4 + r) * 256 + wq * 64 + lane] * sB[r];
        ctx[(tokbase + tok) * 1024 + h * 64 + df * 16 + l15] = f2b(val * rl);
      }
    }
  }
}

// ---------------------------------------------------------------------------
extern "C" void kernel_launch(void* const* d_in, const int* in_sizes, int n_in,
                              void* d_out, int out_size, void* d_ws, size_t ws_size,
                              hipStream_t stream) {
  const float* x      = (const float*)d_in[0];
  const float* ln1_g  = (const float*)d_in[1];
  const float* ln1_b  = (const float*)d_in[2];
  const float* ln2_g  = (const float*)d_in[3];
  const float* ln2_b  = (const float*)d_in[4];
  const float* w_qkv  = (const float*)d_in[5];
  const float* b_qkv  = (const float*)d_in[6];
  const float* w_proj = (const float*)d_in[7];
  const float* b_proj = (const float*)d_in[8];
  const float* w_fc1  = (const float*)d_in[9];
  const float* b_fc1  = (const float*)d_in[10];
  const float* w_fc2  = (const float*)d_in[11];
  const float* b_fc2  = (const float*)d_in[12];
  float* out = (float*)d_out;
  char* ws = (char*)d_ws;
  const size_t MB = 1 << 20;

  // workspace layout (MB offsets), peak 88 MB; aliasing by liveness:
  uint16_t* wTfc1  = (uint16_t*)(ws + 0 * MB);    //  8 MB, dead after fc1
  uint16_t* wTfc2  = (uint16_t*)(ws + 8 * MB);    //  8 MB, live to fc2
  uint16_t* wTqkv  = (uint16_t*)(ws + 16 * MB);   //  6 MB, dead after qkv
  uint16_t* wTproj = (uint16_t*)(ws + 22 * MB);   //  2 MB, dead after proj
  uint16_t* hbuf   = (uint16_t*)(ws + 24 * MB);   //  8 MB, dead after fc1
  uint16_t* qkvb   = (uint16_t*)(ws + 32 * MB);   // 24 MB, dead after attn
  uint16_t* vTb    = (uint16_t*)(ws + 56 * MB);   //  8 MB, dead after attn
  uint16_t* ctxb   = (uint16_t*)(ws + 64 * MB);   //  8 MB, dead after proj
  float*    x2b    = (float*)   (ws + 72 * MB);   // 16 MB, live to reduce
  uint16_t* pp0    = (uint16_t*)(ws + 32 * MB);   //  8 MB proj partial (alias qkvb)
  uint16_t* pp1    = (uint16_t*)(ws + 40 * MB);   //  8 MB proj partial
  uint16_t* actb   = (uint16_t*)(ws + 32 * MB);   // 32 MB fc1 out (alias qkvb/vTb)
  uint16_t* fp0    = (uint16_t*)(ws + 16 * MB);   //  8 MB fc2 partial (alias wTqkv/proj)
  uint16_t* fp1    = (uint16_t*)(ws + 24 * MB);   //  8 MB fc2 partial (alias hbuf)

  k_transpose_all<<<3072, 256, 0, stream>>>(w_qkv, w_proj, w_fc1, w_fc2,
                                            wTqkv, wTproj, wTfc1, wTfc2);

  k_layernorm<<<1024, 256, 0, stream>>>(x, ln1_g, ln1_b, hbuf);
  // qkv GEMM: Q/K cols -> qkvb, V cols -> vTb (transposed in-epilogue)
  k_gemm<3><<<dim3(24, 32), 256, 0, stream>>>(hbuf, wTqkv, b_qkv, qkvb, vTb, 4096, 3072, 1024);
  k_attn<<<dim3(32, 32), 512, 0, stream>>>(qkvb, vTb, ctxb);

  // proj: partials (split-K=2), reduced inside ln2_fuse
  k_gemm_splitk<<<dim3(8, 32, 2), 256, 0, stream>>>(ctxb, wTproj, pp0, pp1,
                                                    4096, 1024, 1024, 512);
  k_ln2_fuse<<<1024, 256, 0, stream>>>(x, pp0, pp1, b_proj, ln2_g, ln2_b, x2b, hbuf);

  k_gemm<2><<<dim3(32, 32), 256, 0, stream>>>(hbuf, wTfc1, b_fc1, actb, nullptr, 4096, 4096, 1024);

  // fc2: partials (split-K=2, Kc=2048), reduced with residual+bias into out
  k_gemm_splitk<<<dim3(8, 32, 2), 256, 0, stream>>>(actb, wTfc2, fp0, fp1,
                                                    4096, 1024, 4096, 2048);
  k_fc2_reduce<<<4096, 256, 0, stream>>>(x2b, fp0, fp1, b_fc2, out, 1024);
}

// Round 15
// 292.755 us; speedup vs baseline: 1.0379x; 1.0111x over previous
//
#include <hip/hip_runtime.h>
#include <hip/hip_bf16.h>
#include <cstdint>

typedef __attribute__((ext_vector_type(8))) short short8;
typedef __attribute__((ext_vector_type(4))) float f32x4;

__device__ __forceinline__ uint16_t f2b(float f) {
  uint32_t u = __builtin_bit_cast(uint32_t, f);
  return (uint16_t)((u + 0x7FFFu + ((u >> 16) & 1u)) >> 16);
}
__device__ __forceinline__ float b2f(uint16_t h) {
  uint32_t u = ((uint32_t)h) << 16;
  return __builtin_bit_cast(float, u);
}
// async global->LDS, 16B per lane. LDS dest must be wave-uniform base + lane*16.
__device__ __forceinline__ void async16(void* lds, const void* g) {
  __builtin_amdgcn_global_load_lds(
      (const __attribute__((address_space(1))) uint32_t*)g,
      (__attribute__((address_space(3))) uint32_t*)lds, 16, 0, 0);
}
// T1: XCD-chunked bijective remap (nwg % 8 == 0 for all our MFMA grids).
__device__ __forceinline__ void xcd_remap(int& bx, int& by, int& bz) {
  int gx = gridDim.x, gy = gridDim.y;
  int nwg = gx * gy * gridDim.z;
  int hw = blockIdx.x + gx * (blockIdx.y + gy * blockIdx.z);
  int work = ((nwg & 7) == 0) ? ((hw & 7) * (nwg >> 3) + (hw >> 3)) : hw;
  bx = work % gx;
  int t = work / gx;
  by = t % gy;
  bz = t / gy;
}

// ------- fused prep: weight transpose+cast (blocks 0..3071) + LN1 (3072+) --
__global__ __launch_bounds__(256) void k_prep(
    const float* __restrict__ wq, const float* __restrict__ wp,
    const float* __restrict__ w1, const float* __restrict__ w2,
    uint16_t* __restrict__ tq, uint16_t* __restrict__ tp,
    uint16_t* __restrict__ t1, uint16_t* __restrict__ t2,
    const float* __restrict__ x, const float* __restrict__ ln1_g,
    const float* __restrict__ ln1_b, uint16_t* __restrict__ hbuf) {
  int id = blockIdx.x;
  if (id >= 3072) {
    // ---- LN1: one wave per row of 1024 ----
    const int row = (id - 3072) * 4 + (threadIdx.x >> 6);
    const int lane = threadIdx.x & 63;
    const float* xr = x + (size_t)row * 1024;
    float4 v[4];
    float s = 0.f, ss = 0.f;
#pragma unroll
    for (int i = 0; i < 4; ++i) {
      v[i] = *(const float4*)&xr[i * 256 + lane * 4];
      s += v[i].x + v[i].y + v[i].z + v[i].w;
      ss += v[i].x * v[i].x + v[i].y * v[i].y + v[i].z * v[i].z + v[i].w * v[i].w;
    }
#pragma unroll
    for (int off = 1; off < 64; off <<= 1) {
      s += __shfl_xor(s, off);
      ss += __shfl_xor(ss, off);
    }
    float mu = s * (1.f / 1024.f);
    float rstd = rsqrtf(ss * (1.f / 1024.f) - mu * mu + 1e-5f);
#pragma unroll
    for (int i = 0; i < 4; ++i) {
      int col = i * 256 + lane * 4;
      float4 gv = *(const float4*)&ln1_g[col];
      float4 bv = *(const float4*)&ln1_b[col];
      ushort4 o;
      o.x = f2b((v[i].x - mu) * rstd * gv.x + bv.x);
      o.y = f2b((v[i].y - mu) * rstd * gv.y + bv.y);
      o.z = f2b((v[i].z - mu) * rstd * gv.z + bv.z);
      o.w = f2b((v[i].w - mu) * rstd * gv.w + bv.w);
      *(ushort4*)&hbuf[(size_t)row * 1024 + col] = o;
    }
    return;
  }
  // ---- transpose+cast: w[K][N] f32 -> wT[N][K] bf16 ----
  __shared__ float tile[64][65];
  const float* w; uint16_t* wT; int K, N, bx, by;
  if (id < 768)        { w = wq; wT = tq; K = 1024; N = 3072; bx = id % 48; by = id / 48; }
  else if (id < 1024)  { id -= 768;  w = wp; wT = tp; K = 1024; N = 1024; bx = id & 15; by = id >> 4; }
  else if (id < 2048)  { id -= 1024; w = w1; wT = t1; K = 1024; N = 4096; bx = id & 63; by = id >> 6; }
  else                 { id -= 2048; w = w2; wT = t2; K = 4096; N = 1024; bx = id & 15; by = id >> 4; }
  const int tx = threadIdx.x;
  const int k0 = by * 64, n0 = bx * 64;
  const int cr = tx & 15, rbase = tx >> 4;
#pragma unroll
  for (int rr = 0; rr < 4; ++rr) {
    int k = rbase + rr * 16;
    int n = cr * 4;
    float4 v = *(const float4*)&w[(size_t)(k0 + k) * N + (n0 + n)];
    tile[k][n + 0] = v.x; tile[k][n + 1] = v.y;
    tile[k][n + 2] = v.z; tile[k][n + 3] = v.w;
  }
  __syncthreads();
#pragma unroll
  for (int rr = 0; rr < 4; ++rr) {
    int n = rbase + rr * 16;
    int k = cr * 4;
    ushort4 o;
    o.x = f2b(tile[k + 0][n]);
    o.y = f2b(tile[k + 1][n]);
    o.z = f2b(tile[k + 2][n]);
    o.w = f2b(tile[k + 3][n]);
    *(ushort4*)&wT[(size_t)(n0 + n) * K + (k0 + k)] = o;
  }
}

// ---------------- ln2 fuse: x2 = x + bias + pp0 + pp1; h = LN(x2)*g+b ------
__global__ __launch_bounds__(256) void k_ln2_fuse(
    const float* __restrict__ x, const uint16_t* __restrict__ pp0,
    const uint16_t* __restrict__ pp1, const float* __restrict__ bias,
    const float* __restrict__ g, const float* __restrict__ b,
    float* __restrict__ x2, uint16_t* __restrict__ out) {
  const int row = blockIdx.x * 4 + (threadIdx.x >> 6);
  const int lane = threadIdx.x & 63;
  const size_t rb = (size_t)row * 1024;
  float4 v[4];
  float s = 0.f, ss = 0.f;
#pragma unroll
  for (int i = 0; i < 4; ++i) {
    int col = i * 256 + lane * 4;
    float4 xv = *(const float4*)&x[rb + col];
    float4 bv = *(const float4*)&bias[col];
    ushort4 a0 = *(const ushort4*)&pp0[rb + col];
    ushort4 a1 = *(const ushort4*)&pp1[rb + col];
    v[i].x = xv.x + bv.x + b2f(a0.x) + b2f(a1.x);
    v[i].y = xv.y + bv.y + b2f(a0.y) + b2f(a1.y);
    v[i].z = xv.z + bv.z + b2f(a0.z) + b2f(a1.z);
    v[i].w = xv.w + bv.w + b2f(a0.w) + b2f(a1.w);
    *(float4*)&x2[rb + col] = v[i];
    s += v[i].x + v[i].y + v[i].z + v[i].w;
    ss += v[i].x * v[i].x + v[i].y * v[i].y + v[i].z * v[i].z + v[i].w * v[i].w;
  }
#pragma unroll
  for (int off = 1; off < 64; off <<= 1) {
    s += __shfl_xor(s, off);
    ss += __shfl_xor(ss, off);
  }
  float mu = s * (1.f / 1024.f);
  float rstd = rsqrtf(ss * (1.f / 1024.f) - mu * mu + 1e-5f);
#pragma unroll
  for (int i = 0; i < 4; ++i) {
    int col = i * 256 + lane * 4;
    float4 gv = *(const float4*)&g[col];
    float4 bv = *(const float4*)&b[col];
    ushort4 o;
    o.x = f2b((v[i].x - mu) * rstd * gv.x + bv.x);
    o.y = f2b((v[i].y - mu) * rstd * gv.y + bv.y);
    o.z = f2b((v[i].z - mu) * rstd * gv.z + bv.z);
    o.w = f2b((v[i].w - mu) * rstd * gv.w + bv.w);
    *(ushort4*)&out[rb + col] = o;
  }
}

// ---------------- fc2 reduce: out = x2 + bias + fp0 + fp1 ------------------
__global__ __launch_bounds__(256) void k_fc2_reduce(
    const float* __restrict__ x2, const uint16_t* __restrict__ f0,
    const uint16_t* __restrict__ f1, const float* __restrict__ bias,
    float* __restrict__ out, int N) {
  int i = (blockIdx.x * 256 + threadIdx.x) * 4;
  float4 v = *(const float4*)&x2[i];
  float4 bv = *(const float4*)&bias[i & (N - 1)];
  ushort4 a0 = *(const ushort4*)&f0[i];
  ushort4 a1 = *(const ushort4*)&f1[i];
  v.x += bv.x + b2f(a0.x) + b2f(a1.x);
  v.y += bv.y + b2f(a0.y) + b2f(a1.y);
  v.z += bv.z + b2f(a0.z) + b2f(a1.z);
  v.w += bv.w + b2f(a0.w) + b2f(a1.w);
  *(float4*)&out[i] = v;
}

// ---------------- GEMM: C[M,N] = A[M,K](bf16) @ Bt[N,K](bf16)^T + bias -----
// EPI 0: bf16 out. EPI 2: bf16 out, tanh-GELU. EPI 3: qkv (V cols -> vT).
template <int EPI>
__global__ __launch_bounds__(256) void k_gemm(
    const uint16_t* __restrict__ A, const uint16_t* __restrict__ Bt,
    const float* __restrict__ bias, void* __restrict__ Cout,
    uint16_t* __restrict__ vTout, int M, int N, int K) {
  __shared__ __align__(16) uint16_t Alds[128 * 64];
  __shared__ __align__(16) uint16_t Blds[128 * 64];
  int bx, by, bz;
  xcd_remap(bx, by, bz);
  const int tid = threadIdx.x;
  const int lane = tid & 63;
  const int w = tid >> 6;
  const int wr = w >> 1, wc = w & 1;
  const int m0 = by * 128, n0 = bx * 128;
  const int l15 = lane & 15, l4 = lane >> 4;
  const uint16_t* pA[4];
  const uint16_t* pB[4];
#pragma unroll
  for (int c = 0; c < 4; ++c) {
    int i = c * 256 + tid;
    int row = i >> 3, d = (i & 7) * 8;
    pA[c] = A + (size_t)(m0 + row) * K + d;
    pB[c] = Bt + (size_t)(n0 + row) * K + d;
  }
  f32x4 acc[4][4] = {};
  for (int k0 = 0; k0 < K; k0 += 64) {
#pragma unroll
    for (int c = 0; c < 4; ++c) {
      async16(&Alds[(c * 256 + tid) * 8], pA[c]);
      pA[c] += 64;
    }
#pragma unroll
    for (int c = 0; c < 4; ++c) {
      async16(&Blds[(c * 256 + tid) * 8], pB[c]);
      pB[c] += 64;
    }
    __syncthreads();
#pragma unroll
    for (int kc = 0; kc < 2; ++kc) {
      short8 af[4], bf[4];
#pragma unroll
      for (int m = 0; m < 4; ++m)
        af[m] = *(const short8*)&Alds[(wr * 64 + m * 16 + l15) * 64 + kc * 32 + l4 * 8];
#pragma unroll
      for (int n = 0; n < 4; ++n)
        bf[n] = *(const short8*)&Blds[(wc * 64 + n * 16 + l15) * 64 + kc * 32 + l4 * 8];
#pragma unroll
      for (int m = 0; m < 4; ++m)
#pragma unroll
        for (int n = 0; n < 4; ++n)
          acc[m][n] = __builtin_amdgcn_mfma_f32_16x16x32_bf16(af[m], bf[n], acc[m][n], 0, 0, 0);
    }
    __syncthreads();
  }
#pragma unroll
  for (int m = 0; m < 4; ++m) {
#pragma unroll
    for (int n = 0; n < 4; ++n) {
      int col = n0 + wc * 64 + n * 16 + l15;
      int rowb = m0 + wr * 64 + m * 16 + l4 * 4;
      float bv = bias[col];
      if constexpr (EPI == 3) {
        if (col >= 2048) {
          int dtot = col - 2048;
          int hh = dtot >> 6, dd = dtot & 63;
          int bg = rowb >> 11, tl = rowb & 2047;
          ushort4 ov;
          ov.x = f2b(acc[m][n][0] + bv);
          ov.y = f2b(acc[m][n][1] + bv);
          ov.z = f2b(acc[m][n][2] + bv);
          ov.w = f2b(acc[m][n][3] + bv);
          *(ushort4*)&vTout[(((size_t)(bg * 16 + hh)) * 64 + dd) * 2048 + tl] = ov;
          continue;
        }
      }
#pragma unroll
      for (int r = 0; r < 4; ++r) {
        float val = acc[m][n][r] + bv;
        size_t idx = (size_t)(rowb + r) * N + col;
        if constexpr (EPI == 2) {
          // tanh-form GELU via exp2
          float u = val * val;
          float a = fmaf(u, 0.1029480545f, 2.3022078158f);
          float t = exp2f(val * a);
          float gl = val - val / (t + 1.0f);
          ((uint16_t*)Cout)[idx] = f2b(gl);
        } else {
          ((uint16_t*)Cout)[idx] = f2b(val);
        }
      }
    }
  }
}

// ---------------- split-K GEMM: bf16 partial per k-slice (no atomics) ------
__global__ __launch_bounds__(256) void k_gemm_splitk(
    const uint16_t* __restrict__ A, const uint16_t* __restrict__ Bt,
    uint16_t* __restrict__ p0, uint16_t* __restrict__ p1,
    int M, int N, int K, int Kc) {
  __shared__ __align__(16) uint16_t Alds[128 * 64];
  __shared__ __align__(16) uint16_t Blds[128 * 64];
  int bx, by, bz;
  xcd_remap(bx, by, bz);
  const int tid = threadIdx.x;
  const int lane = tid & 63;
  const int w = tid >> 6;
  const int wr = w >> 1, wc = w & 1;
  const int m0 = by * 128, n0 = bx * 128;
  const int l15 = lane & 15, l4 = lane >> 4;
  const int kbeg = bz * Kc;
  uint16_t* __restrict__ P = (bz == 0) ? p0 : p1;
  const uint16_t* pA[4];
  const uint16_t* pB[4];
#pragma unroll
  for (int c = 0; c < 4; ++c) {
    int i = c * 256 + tid;
    int row = i >> 3, d = (i & 7) * 8;
    pA[c] = A + (size_t)(m0 + row) * K + kbeg + d;
    pB[c] = Bt + (size_t)(n0 + row) * K + kbeg + d;
  }
  f32x4 acc[4][4] = {};
  for (int k0 = 0; k0 < Kc; k0 += 64) {
#pragma unroll
    for (int c = 0; c < 4; ++c) {
      async16(&Alds[(c * 256 + tid) * 8], pA[c]);
      pA[c] += 64;
    }
#pragma unroll
    for (int c = 0; c < 4; ++c) {
      async16(&Blds[(c * 256 + tid) * 8], pB[c]);
      pB[c] += 64;
    }
    __syncthreads();
#pragma unroll
    for (int kc = 0; kc < 2; ++kc) {
      short8 af[4], bf[4];
#pragma unroll
      for (int m = 0; m < 4; ++m)
        af[m] = *(const short8*)&Alds[(wr * 64 + m * 16 + l15) * 64 + kc * 32 + l4 * 8];
#pragma unroll
      for (int n = 0; n < 4; ++n)
        bf[n] = *(const short8*)&Blds[(wc * 64 + n * 16 + l15) * 64 + kc * 32 + l4 * 8];
#pragma unroll
      for (int m = 0; m < 4; ++m)
#pragma unroll
        for (int n = 0; n < 4; ++n)
          acc[m][n] = __builtin_amdgcn_mfma_f32_16x16x32_bf16(af[m], bf[n], acc[m][n], 0, 0, 0);
    }
    __syncthreads();
  }
#pragma unroll
  for (int m = 0; m < 4; ++m) {
#pragma unroll
    for (int n = 0; n < 4; ++n) {
      int col = n0 + wc * 64 + n * 16 + l15;
      int rowb = m0 + wr * 64 + m * 16 + l4 * 4;
#pragma unroll
      for (int r = 0; r < 4; ++r)
        P[(size_t)(rowb + r) * N + col] = f2b(acc[m][n][r]);
    }
  }
}

// ---------------- flash attention v6 (fastest measured: 77.2-77.8 us) ------
// QBLK=64, 4 waves x 16 q, LDS 40KB -> 4 blocks/CU (16 waves/CU). Swapped
// QK^T, ones-MFMA denominator, defer-max per-lane check, setprio, XOR-
// swizzled K/V staging via global_load_lds, strength-reduced pointers.
// NOTE: grid MUST be dim3(32, 32) — 32 q-tiles of 64 (r14 failure was a
// dim3(16,32) launcher typo leaving half the tokens uncomputed).
__global__ __launch_bounds__(256, 4) void k_attn(
    const uint16_t* __restrict__ qkv, const uint16_t* __restrict__ vT,
    uint16_t* __restrict__ ctx) {
  __shared__ __align__(16) uint16_t Klds[2][64 * 64];
  __shared__ __align__(16) uint16_t Vlds[2][64 * 64];
  __shared__ __align__(16) uint16_t Plds[4][16 * 64];
  int bx, by, bz;
  xcd_remap(bx, by, bz);
  const int bh = by, qt = bx;
  const int b = bh >> 4, h = bh & 15;
  const int tid = threadIdx.x, lane = tid & 63, w = tid >> 6;
  const int l15 = lane & 15, l4 = lane >> 4;
  const int sw = (l15 & 7) << 3;
  const size_t tokbase = (size_t)b * 2048;

  // Q as B-fragment (col=q=l15, k=d), scaled by 0.125*log2e for exp2 domain
  const float QSC = 0.125f * 1.44269504088896340736f;
  short8 qa[2];
  const int qrow = qt * 64 + w * 16 + l15;
#pragma unroll
  for (int kc = 0; kc < 2; ++kc) {
    short8 v = *(const short8*)&qkv[(tokbase + qrow) * 3072 + h * 64 + kc * 32 + l4 * 8];
#pragma unroll
    for (int j = 0; j < 8; ++j) v[j] = (short)f2b(b2f((uint16_t)v[j]) * QSC);
    qa[kc] = v;
  }
  short8 ones;
#pragma unroll
  for (int j = 0; j < 8; ++j) ones[j] = (short)0x3F80;

  float m_s = -1e30f;
  f32x4 o[4] = {};
  f32x4 ol = {};

  // persistent staging pointers (advance per staged tile)
  const uint16_t* pK[2];
  const uint16_t* pV[2];
#pragma unroll
  for (int c = 0; c < 2; ++c) {
    int i = c * 256 + tid;
    int row = i >> 3, colE = (i & 7) * 8;
    int colS = colE ^ ((row & 7) << 3);
    pK[c] = qkv + (tokbase + row) * 3072 + 1024 + h * 64 + colS;
    pV[c] = vT + ((size_t)bh * 64 + row) * 2048 + colS;
  }

  auto stage = [&](int buf) {
#pragma unroll
    for (int c = 0; c < 2; ++c) {
      async16(&Klds[buf][(c * 256 + tid) * 8], pK[c]);
      pK[c] += 64 * 3072;
    }
#pragma unroll
    for (int c = 0; c < 2; ++c) {
      async16(&Vlds[buf][(c * 256 + tid) * 8], pV[c]);
      pV[c] += 64;
    }
  };

  stage(0);
  __syncthreads();
  int cur = 0;

  for (int t0 = 0; t0 < 2048; t0 += 64) {
    if (t0 + 64 < 2048) stage(cur ^ 1);

    // S^T = K @ Q^T
    f32x4 s[4] = {};
    __builtin_amdgcn_s_setprio(1);
#pragma unroll
    for (int kc = 0; kc < 2; ++kc) {
      const int cc = (kc * 32 + l4 * 8) ^ sw;
#pragma unroll
      for (int c = 0; c < 4; ++c) {
        short8 kf = *(const short8*)&Klds[cur][(c * 16 + l15) * 64 + cc];
        s[c] = __builtin_amdgcn_mfma_f32_16x16x32_bf16(kf, qa[kc], s[c], 0, 0, 0);
      }
    }
    __builtin_amdgcn_s_setprio(0);

    // online softmax: lane owns q-row l15 (16 key-values in regs)
    {
      float a0 = fmaxf(fmaxf(s[0][0], s[0][1]), fmaxf(s[0][2], s[0][3]));
      float a1 = fmaxf(fmaxf(s[1][0], s[1][1]), fmaxf(s[1][2], s[1][3]));
      float a2 = fmaxf(fmaxf(s[2][0], s[2][1]), fmaxf(s[2][2], s[2][3]));
      float a3 = fmaxf(fmaxf(s[3][0], s[3][1]), fmaxf(s[3][2], s[3][3]));
      float pml = fmaxf(fmaxf(a0, a1), fmaxf(a2, a3));  // partial (lane) max
      if (!__all(pml - m_s <= 8.f)) {
        float pm = pml;
        pm = fmaxf(pm, __shfl_xor(pm, 16));
        pm = fmaxf(pm, __shfl_xor(pm, 32));
        float mn = fmaxf(m_s, pm);
        float scale = exp2f(m_s - mn);
        m_s = mn;
        float sc0 = __shfl(scale, l4 * 4 + 0);
        float sc1 = __shfl(scale, l4 * 4 + 1);
        float sc2 = __shfl(scale, l4 * 4 + 2);
        float sc3 = __shfl(scale, l4 * 4 + 3);
#pragma unroll
        for (int df = 0; df < 4; ++df) {
          o[df][0] *= sc0; o[df][1] *= sc1; o[df][2] *= sc2; o[df][3] *= sc3;
        }
        ol[0] *= sc0; ol[1] *= sc1; ol[2] *= sc2; ol[3] *= sc3;
      }
#pragma unroll
      for (int c = 0; c < 4; ++c) {
        float p0 = exp2f(s[c][0] - m_s);
        float p1 = exp2f(s[c][1] - m_s);
        float p2 = exp2f(s[c][2] - m_s);
        float p3 = exp2f(s[c][3] - m_s);
        uint32_t lo, hi;
        asm("v_cvt_pk_bf16_f32 %0, %1, %2" : "=v"(lo) : "v"(p0), "v"(p1));
        asm("v_cvt_pk_bf16_f32 %0, %1, %2" : "=v"(hi) : "v"(p2), "v"(p3));
        *(uint2*)&Plds[w][l15 * 64 + ((c * 16 + l4 * 4) ^ sw)] = make_uint2(lo, hi);
      }
    }

    // O += P @ V; l += P @ ones (same D-layout as O)
    __builtin_amdgcn_s_setprio(1);
#pragma unroll
    for (int kc = 0; kc < 2; ++kc) {
      const int cc = (kc * 32 + l4 * 8) ^ sw;
      short8 pa = *(const short8*)&Plds[w][l15 * 64 + cc];
      ol = __builtin_amdgcn_mfma_f32_16x16x32_bf16(pa, ones, ol, 0, 0, 0);
#pragma unroll
      for (int df = 0; df < 4; ++df) {
        short8 vf = *(const short8*)&Vlds[cur][(df * 16 + l15) * 64 + cc];
        o[df] = __builtin_amdgcn_mfma_f32_16x16x32_bf16(pa, vf, o[df], 0, 0, 0);
      }
    }
    __builtin_amdgcn_s_setprio(0);
    __syncthreads();
    cur ^= 1;
  }

  // epilogue: ol[r] is the denominator for q-row l4*4+r (replicated over l15)
#pragma unroll
  for (int r = 0; r < 4; ++r) {
    float rl = 1.0f / ol[r];
    int tok = qt * 64 + w * 16 + l4 * 4 + r;
#pragma unroll
    for (int df = 0; df < 4; ++df) {
      ctx[(tokbase + tok) * 1024 + h * 64 + df * 16 + l15] = f2b(o[df][r] * rl);
    }
  }
}

// ---------------------------------------------------------------------------
extern "C" void kernel_launch(void* const* d_in, const int* in_sizes, int n_in,
                              void* d_out, int out_size, void* d_ws, size_t ws_size,
                              hipStream_t stream) {
  const float* x      = (const float*)d_in[0];
  const float* ln1_g  = (const float*)d_in[1];
  const float* ln1_b  = (const float*)d_in[2];
  const float* ln2_g  = (const float*)d_in[3];
  const float* ln2_b  = (const float*)d_in[4];
  const float* w_qkv  = (const float*)d_in[5];
  const float* b_qkv  = (const float*)d_in[6];
  const float* w_proj = (const float*)d_in[7];
  const float* b_proj = (const float*)d_in[8];
  const float* w_fc1  = (const float*)d_in[9];
  const float* b_fc1  = (const float*)d_in[10];
  const float* w_fc2  = (const float*)d_in[11];
  const float* b_fc2  = (const float*)d_in[12];
  float* out = (float*)d_out;
  char* ws = (char*)d_ws;
  const size_t MB = 1 << 20;

  // workspace layout (MB offsets), peak 88 MB; aliasing by liveness:
  uint16_t* wTfc1  = (uint16_t*)(ws + 0 * MB);    //  8 MB, dead after fc1
  uint16_t* wTfc2  = (uint16_t*)(ws + 8 * MB);    //  8 MB, live to fc2
  uint16_t* wTqkv  = (uint16_t*)(ws + 16 * MB);   //  6 MB, dead after qkv
  uint16_t* wTproj = (uint16_t*)(ws + 22 * MB);   //  2 MB, dead after proj
  uint16_t* hbuf   = (uint16_t*)(ws + 24 * MB);   //  8 MB, dead after fc1
  uint16_t* qkvb   = (uint16_t*)(ws + 32 * MB);   // 24 MB, dead after attn
  uint16_t* vTb    = (uint16_t*)(ws + 56 * MB);   //  8 MB, dead after attn
  uint16_t* ctxb   = (uint16_t*)(ws + 64 * MB);   //  8 MB, dead after proj
  float*    x2b    = (float*)   (ws + 72 * MB);   // 16 MB, live to reduce
  uint16_t* pp0    = (uint16_t*)(ws + 32 * MB);   //  8 MB proj partial (alias qkvb)
  uint16_t* pp1    = (uint16_t*)(ws + 40 * MB);   //  8 MB proj partial
  uint16_t* actb   = (uint16_t*)(ws + 32 * MB);   // 32 MB fc1 out (alias qkvb/vTb)
  uint16_t* fp0    = (uint16_t*)(ws + 16 * MB);   //  8 MB fc2 partial (alias wTqkv/proj)
  uint16_t* fp1    = (uint16_t*)(ws + 24 * MB);   //  8 MB fc2 partial (alias hbuf)

  // prep: all 4 weight transposes + LN1 in one dispatch
  k_prep<<<4096, 256, 0, stream>>>(w_qkv, w_proj, w_fc1, w_fc2,
                                   wTqkv, wTproj, wTfc1, wTfc2,
                                   x, ln1_g, ln1_b, hbuf);

  // qkv GEMM: Q/K cols -> qkvb, V cols -> vTb (transposed in-epilogue)
  k_gemm<3><<<dim3(24, 32), 256, 0, stream>>>(hbuf, wTqkv, b_qkv, qkvb, vTb, 4096, 3072, 1024);
  k_attn<<<dim3(32, 32), 256, 0, stream>>>(qkvb, vTb, ctxb);

  // proj: partials (split-K=2), reduced inside ln2_fuse
  k_gemm_splitk<<<dim3(8, 32, 2), 256, 0, stream>>>(ctxb, wTproj, pp0, pp1,
                                                    4096, 1024, 1024, 512);
  k_ln2_fuse<<<1024, 256, 0, stream>>>(x, pp0, pp1, b_proj, ln2_g, ln2_b, x2b, hbuf);

  k_gemm<2><<<dim3(32, 32), 256, 0, stream>>>(hbuf, wTfc1, b_fc1, actb, nullptr, 4096, 4096, 1024);

  // fc2: partials (split-K=2, Kc=2048), reduced with residual+bias into out
  k_gemm_splitk<<<dim3(8, 32, 2), 256, 0, stream>>>(actb, wTfc2, fp0, fp1,
                                                    4096, 1024, 4096, 2048);
  k_fc2_reduce<<<4096, 256, 0, stream>>>(x2b, fp0, fp1, b_fc2, out, 1024);
}

// Round 16
// 290.154 us; speedup vs baseline: 1.0472x; 1.0090x over previous
//
#include <hip/hip_runtime.h>
#include <hip/hip_bf16.h>
#include <cstdint>

typedef __attribute__((ext_vector_type(8))) short short8;
typedef __attribute__((ext_vector_type(4))) float f32x4;

__device__ __forceinline__ uint16_t f2b(float f) {
  uint32_t u = __builtin_bit_cast(uint32_t, f);
  return (uint16_t)((u + 0x7FFFu + ((u >> 16) & 1u)) >> 16);
}
__device__ __forceinline__ float b2f(uint16_t h) {
  uint32_t u = ((uint32_t)h) << 16;
  return __builtin_bit_cast(float, u);
}
// async global->LDS, 16B per lane. LDS dest must be wave-uniform base + lane*16.
__device__ __forceinline__ void async16(void* lds, const void* g) {
  __builtin_amdgcn_global_load_lds(
      (const __attribute__((address_space(1))) uint32_t*)g,
      (__attribute__((address_space(3))) uint32_t*)lds, 16, 0, 0);
}
// T1: XCD-chunked bijective remap (nwg % 8 == 0 for all our MFMA grids).
__device__ __forceinline__ void xcd_remap(int& bx, int& by, int& bz) {
  int gx = gridDim.x, gy = gridDim.y;
  int nwg = gx * gy * gridDim.z;
  int hw = blockIdx.x + gx * (blockIdx.y + gy * blockIdx.z);
  int work = ((nwg & 7) == 0) ? ((hw & 7) * (nwg >> 3) + (hw >> 3)) : hw;
  bx = work % gx;
  int t = work / gx;
  by = t % gy;
  bz = t / gy;
}

// ------- fused prep: weight transpose+cast (blocks 0..3071) + LN1 (3072+) --
__global__ __launch_bounds__(256) void k_prep(
    const float* __restrict__ wq, const float* __restrict__ wp,
    const float* __restrict__ w1, const float* __restrict__ w2,
    uint16_t* __restrict__ tq, uint16_t* __restrict__ tp,
    uint16_t* __restrict__ t1, uint16_t* __restrict__ t2,
    const float* __restrict__ x, const float* __restrict__ ln1_g,
    const float* __restrict__ ln1_b, uint16_t* __restrict__ hbuf) {
  int id = blockIdx.x;
  if (id >= 3072) {
    // ---- LN1: one wave per row of 1024 ----
    const int row = (id - 3072) * 4 + (threadIdx.x >> 6);
    const int lane = threadIdx.x & 63;
    const float* xr = x + (size_t)row * 1024;
    float4 v[4];
    float s = 0.f, ss = 0.f;
#pragma unroll
    for (int i = 0; i < 4; ++i) {
      v[i] = *(const float4*)&xr[i * 256 + lane * 4];
      s += v[i].x + v[i].y + v[i].z + v[i].w;
      ss += v[i].x * v[i].x + v[i].y * v[i].y + v[i].z * v[i].z + v[i].w * v[i].w;
    }
#pragma unroll
    for (int off = 1; off < 64; off <<= 1) {
      s += __shfl_xor(s, off);
      ss += __shfl_xor(ss, off);
    }
    float mu = s * (1.f / 1024.f);
    float rstd = rsqrtf(ss * (1.f / 1024.f) - mu * mu + 1e-5f);
#pragma unroll
    for (int i = 0; i < 4; ++i) {
      int col = i * 256 + lane * 4;
      float4 gv = *(const float4*)&ln1_g[col];
      float4 bv = *(const float4*)&ln1_b[col];
      ushort4 o;
      o.x = f2b((v[i].x - mu) * rstd * gv.x + bv.x);
      o.y = f2b((v[i].y - mu) * rstd * gv.y + bv.y);
      o.z = f2b((v[i].z - mu) * rstd * gv.z + bv.z);
      o.w = f2b((v[i].w - mu) * rstd * gv.w + bv.w);
      *(ushort4*)&hbuf[(size_t)row * 1024 + col] = o;
    }
    return;
  }
  // ---- transpose+cast: w[K][N] f32 -> wT[N][K] bf16 ----
  __shared__ float tile[64][65];
  const float* w; uint16_t* wT; int K, N, bx, by;
  if (id < 768)        { w = wq; wT = tq; K = 1024; N = 3072; bx = id % 48; by = id / 48; }
  else if (id < 1024)  { id -= 768;  w = wp; wT = tp; K = 1024; N = 1024; bx = id & 15; by = id >> 4; }
  else if (id < 2048)  { id -= 1024; w = w1; wT = t1; K = 1024; N = 4096; bx = id & 63; by = id >> 6; }
  else                 { id -= 2048; w = w2; wT = t2; K = 4096; N = 1024; bx = id & 15; by = id >> 4; }
  const int tx = threadIdx.x;
  const int k0 = by * 64, n0 = bx * 64;
  const int cr = tx & 15, rbase = tx >> 4;
#pragma unroll
  for (int rr = 0; rr < 4; ++rr) {
    int k = rbase + rr * 16;
    int n = cr * 4;
    float4 v = *(const float4*)&w[(size_t)(k0 + k) * N + (n0 + n)];
    tile[k][n + 0] = v.x; tile[k][n + 1] = v.y;
    tile[k][n + 2] = v.z; tile[k][n + 3] = v.w;
  }
  __syncthreads();
#pragma unroll
  for (int rr = 0; rr < 4; ++rr) {
    int n = rbase + rr * 16;
    int k = cr * 4;
    ushort4 o;
    o.x = f2b(tile[k + 0][n]);
    o.y = f2b(tile[k + 1][n]);
    o.z = f2b(tile[k + 2][n]);
    o.w = f2b(tile[k + 3][n]);
    *(ushort4*)&wT[(size_t)(n0 + n) * K + (k0 + k)] = o;
  }
}

// ---- ln2 fuse: x2(bf16) = x + bias + pp0 + pp1; h = LN(x2)*g+b ------------
// LN2 uses full f32 values in registers; only the stored residual is bf16.
__global__ __launch_bounds__(256) void k_ln2_fuse(
    const float* __restrict__ x, const uint16_t* __restrict__ pp0,
    const uint16_t* __restrict__ pp1, const float* __restrict__ bias,
    const float* __restrict__ g, const float* __restrict__ b,
    uint16_t* __restrict__ x2, uint16_t* __restrict__ out) {
  const int row = blockIdx.x * 4 + (threadIdx.x >> 6);
  const int lane = threadIdx.x & 63;
  const size_t rb = (size_t)row * 1024;
  float4 v[4];
  float s = 0.f, ss = 0.f;
#pragma unroll
  for (int i = 0; i < 4; ++i) {
    int col = i * 256 + lane * 4;
    float4 xv = *(const float4*)&x[rb + col];
    float4 bv = *(const float4*)&bias[col];
    ushort4 a0 = *(const ushort4*)&pp0[rb + col];
    ushort4 a1 = *(const ushort4*)&pp1[rb + col];
    v[i].x = xv.x + bv.x + b2f(a0.x) + b2f(a1.x);
    v[i].y = xv.y + bv.y + b2f(a0.y) + b2f(a1.y);
    v[i].z = xv.z + bv.z + b2f(a0.z) + b2f(a1.z);
    v[i].w = xv.w + bv.w + b2f(a0.w) + b2f(a1.w);
    ushort4 xo;
    xo.x = f2b(v[i].x); xo.y = f2b(v[i].y); xo.z = f2b(v[i].z); xo.w = f2b(v[i].w);
    *(ushort4*)&x2[rb + col] = xo;
    s += v[i].x + v[i].y + v[i].z + v[i].w;
    ss += v[i].x * v[i].x + v[i].y * v[i].y + v[i].z * v[i].z + v[i].w * v[i].w;
  }
#pragma unroll
  for (int off = 1; off < 64; off <<= 1) {
    s += __shfl_xor(s, off);
    ss += __shfl_xor(ss, off);
  }
  float mu = s * (1.f / 1024.f);
  float rstd = rsqrtf(ss * (1.f / 1024.f) - mu * mu + 1e-5f);
#pragma unroll
  for (int i = 0; i < 4; ++i) {
    int col = i * 256 + lane * 4;
    float4 gv = *(const float4*)&g[col];
    float4 bv = *(const float4*)&b[col];
    ushort4 o;
    o.x = f2b((v[i].x - mu) * rstd * gv.x + bv.x);
    o.y = f2b((v[i].y - mu) * rstd * gv.y + bv.y);
    o.z = f2b((v[i].z - mu) * rstd * gv.z + bv.z);
    o.w = f2b((v[i].w - mu) * rstd * gv.w + bv.w);
    *(ushort4*)&out[rb + col] = o;
  }
}

// ---------------- fc2 reduce: out = x2(bf16) + bias + fp0 + fp1 ------------
__global__ __launch_bounds__(256) void k_fc2_reduce(
    const uint16_t* __restrict__ x2, const uint16_t* __restrict__ f0,
    const uint16_t* __restrict__ f1, const float* __restrict__ bias,
    float* __restrict__ out, int N) {
  int i = (blockIdx.x * 256 + threadIdx.x) * 4;
  ushort4 xv = *(const ushort4*)&x2[i];
  float4 bv = *(const float4*)&bias[i & (N - 1)];
  ushort4 a0 = *(const ushort4*)&f0[i];
  ushort4 a1 = *(const ushort4*)&f1[i];
  float4 v;
  v.x = b2f(xv.x) + bv.x + b2f(a0.x) + b2f(a1.x);
  v.y = b2f(xv.y) + bv.y + b2f(a0.y) + b2f(a1.y);
  v.z = b2f(xv.z) + bv.z + b2f(a0.z) + b2f(a1.z);
  v.w = b2f(xv.w) + bv.w + b2f(a0.w) + b2f(a1.w);
  *(float4*)&out[i] = v;
}

// ---------------- GEMM: C[M,N] = A[M,K](bf16) @ Bt[N,K](bf16)^T + bias -----
// EPI 0: bf16 out. EPI 2: bf16 out, tanh-GELU. EPI 3: qkv (V cols -> vT).
template <int EPI>
__global__ __launch_bounds__(256) void k_gemm(
    const uint16_t* __restrict__ A, const uint16_t* __restrict__ Bt,
    const float* __restrict__ bias, void* __restrict__ Cout,
    uint16_t* __restrict__ vTout, int M, int N, int K) {
  __shared__ __align__(16) uint16_t Alds[128 * 64];
  __shared__ __align__(16) uint16_t Blds[128 * 64];
  int bx, by, bz;
  xcd_remap(bx, by, bz);
  const int tid = threadIdx.x;
  const int lane = tid & 63;
  const int w = tid >> 6;
  const int wr = w >> 1, wc = w & 1;
  const int m0 = by * 128, n0 = bx * 128;
  const int l15 = lane & 15, l4 = lane >> 4;
  const uint16_t* pA[4];
  const uint16_t* pB[4];
#pragma unroll
  for (int c = 0; c < 4; ++c) {
    int i = c * 256 + tid;
    int row = i >> 3, d = (i & 7) * 8;
    pA[c] = A + (size_t)(m0 + row) * K + d;
    pB[c] = Bt + (size_t)(n0 + row) * K + d;
  }
  f32x4 acc[4][4] = {};
  for (int k0 = 0; k0 < K; k0 += 64) {
#pragma unroll
    for (int c = 0; c < 4; ++c) {
      async16(&Alds[(c * 256 + tid) * 8], pA[c]);
      pA[c] += 64;
    }
#pragma unroll
    for (int c = 0; c < 4; ++c) {
      async16(&Blds[(c * 256 + tid) * 8], pB[c]);
      pB[c] += 64;
    }
    __syncthreads();
#pragma unroll
    for (int kc = 0; kc < 2; ++kc) {
      short8 af[4], bf[4];
#pragma unroll
      for (int m = 0; m < 4; ++m)
        af[m] = *(const short8*)&Alds[(wr * 64 + m * 16 + l15) * 64 + kc * 32 + l4 * 8];
#pragma unroll
      for (int n = 0; n < 4; ++n)
        bf[n] = *(const short8*)&Blds[(wc * 64 + n * 16 + l15) * 64 + kc * 32 + l4 * 8];
#pragma unroll
      for (int m = 0; m < 4; ++m)
#pragma unroll
        for (int n = 0; n < 4; ++n)
          acc[m][n] = __builtin_amdgcn_mfma_f32_16x16x32_bf16(af[m], bf[n], acc[m][n], 0, 0, 0);
    }
    __syncthreads();
  }
#pragma unroll
  for (int m = 0; m < 4; ++m) {
#pragma unroll
    for (int n = 0; n < 4; ++n) {
      int col = n0 + wc * 64 + n * 16 + l15;
      int rowb = m0 + wr * 64 + m * 16 + l4 * 4;
      float bv = bias[col];
      if constexpr (EPI == 3) {
        if (col >= 2048) {
          int dtot = col - 2048;
          int hh = dtot >> 6, dd = dtot & 63;
          int bg = rowb >> 11, tl = rowb & 2047;
          ushort4 ov;
          ov.x = f2b(acc[m][n][0] + bv);
          ov.y = f2b(acc[m][n][1] + bv);
          ov.z = f2b(acc[m][n][2] + bv);
          ov.w = f2b(acc[m][n][3] + bv);
          *(ushort4*)&vTout[(((size_t)(bg * 16 + hh)) * 64 + dd) * 2048 + tl] = ov;
          continue;
        }
      }
#pragma unroll
      for (int r = 0; r < 4; ++r) {
        float val = acc[m][n][r] + bv;
        size_t idx = (size_t)(rowb + r) * N + col;
        if constexpr (EPI == 2) {
          // tanh-form GELU via exp2
          float u = val * val;
          float a = fmaf(u, 0.1029480545f, 2.3022078158f);
          float t = exp2f(val * a);
          float gl = val - val / (t + 1.0f);
          ((uint16_t*)Cout)[idx] = f2b(gl);
        } else {
          ((uint16_t*)Cout)[idx] = f2b(val);
        }
      }
    }
  }
}

// ---------------- split-K GEMM: bf16 partial per k-slice (no atomics) ------
__global__ __launch_bounds__(256) void k_gemm_splitk(
    const uint16_t* __restrict__ A, const uint16_t* __restrict__ Bt,
    uint16_t* __restrict__ p0, uint16_t* __restrict__ p1,
    int M, int N, int K, int Kc) {
  __shared__ __align__(16) uint16_t Alds[128 * 64];
  __shared__ __align__(16) uint16_t Blds[128 * 64];
  int bx, by, bz;
  xcd_remap(bx, by, bz);
  const int tid = threadIdx.x;
  const int lane = tid & 63;
  const int w = tid >> 6;
  const int wr = w >> 1, wc = w & 1;
  const int m0 = by * 128, n0 = bx * 128;
  const int l15 = lane & 15, l4 = lane >> 4;
  const int kbeg = bz * Kc;
  uint16_t* __restrict__ P = (bz == 0) ? p0 : p1;
  const uint16_t* pA[4];
  const uint16_t* pB[4];
#pragma unroll
  for (int c = 0; c < 4; ++c) {
    int i = c * 256 + tid;
    int row = i >> 3, d = (i & 7) * 8;
    pA[c] = A + (size_t)(m0 + row) * K + kbeg + d;
    pB[c] = Bt + (size_t)(n0 + row) * K + kbeg + d;
  }
  f32x4 acc[4][4] = {};
  for (int k0 = 0; k0 < Kc; k0 += 64) {
#pragma unroll
    for (int c = 0; c < 4; ++c) {
      async16(&Alds[(c * 256 + tid) * 8], pA[c]);
      pA[c] += 64;
    }
#pragma unroll
    for (int c = 0; c < 4; ++c) {
      async16(&Blds[(c * 256 + tid) * 8], pB[c]);
      pB[c] += 64;
    }
    __syncthreads();
#pragma unroll
    for (int kc = 0; kc < 2; ++kc) {
      short8 af[4], bf[4];
#pragma unroll
      for (int m = 0; m < 4; ++m)
        af[m] = *(const short8*)&Alds[(wr * 64 + m * 16 + l15) * 64 + kc * 32 + l4 * 8];
#pragma unroll
      for (int n = 0; n < 4; ++n)
        bf[n] = *(const short8*)&Blds[(wc * 64 + n * 16 + l15) * 64 + kc * 32 + l4 * 8];
#pragma unroll
      for (int m = 0; m < 4; ++m)
#pragma unroll
        for (int n = 0; n < 4; ++n)
          acc[m][n] = __builtin_amdgcn_mfma_f32_16x16x32_bf16(af[m], bf[n], acc[m][n], 0, 0, 0);
    }
    __syncthreads();
  }
#pragma unroll
  for (int m = 0; m < 4; ++m) {
#pragma unroll
    for (int n = 0; n < 4; ++n) {
      int col = n0 + wc * 64 + n * 16 + l15;
      int rowb = m0 + wr * 64 + m * 16 + l4 * 4;
#pragma unroll
      for (int r = 0; r < 4; ++r)
        P[(size_t)(rowb + r) * N + col] = f2b(acc[m][n][r]);
    }
  }
}

// ---------------- flash attention v6 (fastest measured: 77.0-77.8 us) ------
// QBLK=64, 4 waves x 16 q, LDS 40KB -> 4 blocks/CU (16 waves/CU). Swapped
// QK^T, ones-MFMA denominator, defer-max per-lane check, setprio, XOR-
// swizzled K/V staging via global_load_lds, strength-reduced pointers.
// NOTE: grid MUST be dim3(32, 32) — 32 q-tiles of 64 (r14 failure was a
// dim3(16,32) launcher typo leaving half the tokens uncomputed).
__global__ __launch_bounds__(256, 4) void k_attn(
    const uint16_t* __restrict__ qkv, const uint16_t* __restrict__ vT,
    uint16_t* __restrict__ ctx) {
  __shared__ __align__(16) uint16_t Klds[2][64 * 64];
  __shared__ __align__(16) uint16_t Vlds[2][64 * 64];
  __shared__ __align__(16) uint16_t Plds[4][16 * 64];
  int bx, by, bz;
  xcd_remap(bx, by, bz);
  const int bh = by, qt = bx;
  const int b = bh >> 4, h = bh & 15;
  const int tid = threadIdx.x, lane = tid & 63, w = tid >> 6;
  const int l15 = lane & 15, l4 = lane >> 4;
  const int sw = (l15 & 7) << 3;
  const size_t tokbase = (size_t)b * 2048;

  // Q as B-fragment (col=q=l15, k=d), scaled by 0.125*log2e for exp2 domain
  const float QSC = 0.125f * 1.44269504088896340736f;
  short8 qa[2];
  const int qrow = qt * 64 + w * 16 + l15;
#pragma unroll
  for (int kc = 0; kc < 2; ++kc) {
    short8 v = *(const short8*)&qkv[(tokbase + qrow) * 3072 + h * 64 + kc * 32 + l4 * 8];
#pragma unroll
    for (int j = 0; j < 8; ++j) v[j] = (short)f2b(b2f((uint16_t)v[j]) * QSC);
    qa[kc] = v;
  }
  short8 ones;
#pragma unroll
  for (int j = 0; j < 8; ++j) ones[j] = (short)0x3F80;

  float m_s = -1e30f;
  f32x4 o[4] = {};
  f32x4 ol = {};

  // persistent staging pointers (advance per staged tile)
  const uint16_t* pK[2];
  const uint16_t* pV[2];
#pragma unroll
  for (int c = 0; c < 2; ++c) {
    int i = c * 256 + tid;
    int row = i >> 3, colE = (i & 7) * 8;
    int colS = colE ^ ((row & 7) << 3);
    pK[c] = qkv + (tokbase + row) * 3072 + 1024 + h * 64 + colS;
    pV[c] = vT + ((size_t)bh * 64 + row) * 2048 + colS;
  }

  auto stage = [&](int buf) {
#pragma unroll
    for (int c = 0; c < 2; ++c) {
      async16(&Klds[buf][(c * 256 + tid) * 8], pK[c]);
      pK[c] += 64 * 3072;
    }
#pragma unroll
    for (int c = 0; c < 2; ++c) {
      async16(&Vlds[buf][(c * 256 + tid) * 8], pV[c]);
      pV[c] += 64;
    }
  };

  stage(0);
  __syncthreads();
  int cur = 0;

  for (int t0 = 0; t0 < 2048; t0 += 64) {
    if (t0 + 64 < 2048) stage(cur ^ 1);

    // S^T = K @ Q^T
    f32x4 s[4] = {};
    __builtin_amdgcn_s_setprio(1);
#pragma unroll
    for (int kc = 0; kc < 2; ++kc) {
      const int cc = (kc * 32 + l4 * 8) ^ sw;
#pragma unroll
      for (int c = 0; c < 4; ++c) {
        short8 kf = *(const short8*)&Klds[cur][(c * 16 + l15) * 64 + cc];
        s[c] = __builtin_amdgcn_mfma_f32_16x16x32_bf16(kf, qa[kc], s[c], 0, 0, 0);
      }
    }
    __builtin_amdgcn_s_setprio(0);

    // online softmax: lane owns q-row l15 (16 key-values in regs)
    {
      float a0 = fmaxf(fmaxf(s[0][0], s[0][1]), fmaxf(s[0][2], s[0][3]));
      float a1 = fmaxf(fmaxf(s[1][0], s[1][1]), fmaxf(s[1][2], s[1][3]));
      float a2 = fmaxf(fmaxf(s[2][0], s[2][1]), fmaxf(s[2][2], s[2][3]));
      float a3 = fmaxf(fmaxf(s[3][0], s[3][1]), fmaxf(s[3][2], s[3][3]));
      float pml = fmaxf(fmaxf(a0, a1), fmaxf(a2, a3));  // partial (lane) max
      if (!__all(pml - m_s <= 8.f)) {
        float pm = pml;
        pm = fmaxf(pm, __shfl_xor(pm, 16));
        pm = fmaxf(pm, __shfl_xor(pm, 32));
        float mn = fmaxf(m_s, pm);
        float scale = exp2f(m_s - mn);
        m_s = mn;
        float sc0 = __shfl(scale, l4 * 4 + 0);
        float sc1 = __shfl(scale, l4 * 4 + 1);
        float sc2 = __shfl(scale, l4 * 4 + 2);
        float sc3 = __shfl(scale, l4 * 4 + 3);
#pragma unroll
        for (int df = 0; df < 4; ++df) {
          o[df][0] *= sc0; o[df][1] *= sc1; o[df][2] *= sc2; o[df][3] *= sc3;
        }
        ol[0] *= sc0; ol[1] *= sc1; ol[2] *= sc2; ol[3] *= sc3;
      }
#pragma unroll
      for (int c = 0; c < 4; ++c) {
        float p0 = exp2f(s[c][0] - m_s);
        float p1 = exp2f(s[c][1] - m_s);
        float p2 = exp2f(s[c][2] - m_s);
        float p3 = exp2f(s[c][3] - m_s);
        uint32_t lo, hi;
        asm("v_cvt_pk_bf16_f32 %0, %1, %2" : "=v"(lo) : "v"(p0), "v"(p1));
        asm("v_cvt_pk_bf16_f32 %0, %1, %2" : "=v"(hi) : "v"(p2), "v"(p3));
        *(uint2*)&Plds[w][l15 * 64 + ((c * 16 + l4 * 4) ^ sw)] = make_uint2(lo, hi);
      }
    }

    // O += P @ V; l += P @ ones (same D-layout as O)
    __builtin_amdgcn_s_setprio(1);
#pragma unroll
    for (int kc = 0; kc < 2; ++kc) {
      const int cc = (kc * 32 + l4 * 8) ^ sw;
      short8 pa = *(const short8*)&Plds[w][l15 * 64 + cc];
      ol = __builtin_amdgcn_mfma_f32_16x16x32_bf16(pa, ones, ol, 0, 0, 0);
#pragma unroll
      for (int df = 0; df < 4; ++df) {
        short8 vf = *(const short8*)&Vlds[cur][(df * 16 + l15) * 64 + cc];
        o[df] = __builtin_amdgcn_mfma_f32_16x16x32_bf16(pa, vf, o[df], 0, 0, 0);
      }
    }
    __builtin_amdgcn_s_setprio(0);
    __syncthreads();
    cur ^= 1;
  }

  // epilogue: ol[r] is the denominator for q-row l4*4+r (replicated over l15)
#pragma unroll
  for (int r = 0; r < 4; ++r) {
    float rl = 1.0f / ol[r];
    int tok = qt * 64 + w * 16 + l4 * 4 + r;
#pragma unroll
    for (int df = 0; df < 4; ++df) {
      ctx[(tokbase + tok) * 1024 + h * 64 + df * 16 + l15] = f2b(o[df][r] * rl);
    }
  }
}

// ---------------------------------------------------------------------------
extern "C" void kernel_launch(void* const* d_in, const int* in_sizes, int n_in,
                              void* d_out, int out_size, void* d_ws, size_t ws_size,
                              hipStream_t stream) {
  const float* x      = (const float*)d_in[0];
  const float* ln1_g  = (const float*)d_in[1];
  const float* ln1_b  = (const float*)d_in[2];
  const float* ln2_g  = (const float*)d_in[3];
  const float* ln2_b  = (const float*)d_in[4];
  const float* w_qkv  = (const float*)d_in[5];
  const float* b_qkv  = (const float*)d_in[6];
  const float* w_proj = (const float*)d_in[7];
  const float* b_proj = (const float*)d_in[8];
  const float* w_fc1  = (const float*)d_in[9];
  const float* b_fc1  = (const float*)d_in[10];
  const float* w_fc2  = (const float*)d_in[11];
  const float* b_fc2  = (const float*)d_in[12];
  float* out = (float*)d_out;
  char* ws = (char*)d_ws;
  const size_t MB = 1 << 20;

  // workspace layout (MB offsets), peak 80 MB; aliasing by liveness:
  uint16_t* wTfc1  = (uint16_t*)(ws + 0 * MB);    //  8 MB, dead after fc1
  uint16_t* wTfc2  = (uint16_t*)(ws + 8 * MB);    //  8 MB, live to fc2
  uint16_t* wTqkv  = (uint16_t*)(ws + 16 * MB);   //  6 MB, dead after qkv
  uint16_t* wTproj = (uint16_t*)(ws + 22 * MB);   //  2 MB, dead after proj
  uint16_t* hbuf   = (uint16_t*)(ws + 24 * MB);   //  8 MB, dead after fc1
  uint16_t* qkvb   = (uint16_t*)(ws + 32 * MB);   // 24 MB, dead after attn
  uint16_t* vTb    = (uint16_t*)(ws + 56 * MB);   //  8 MB, dead after attn
  uint16_t* ctxb   = (uint16_t*)(ws + 64 * MB);   //  8 MB, dead after proj
  uint16_t* x2b    = (uint16_t*)(ws + 72 * MB);   //  8 MB bf16, live to reduce
  uint16_t* pp0    = (uint16_t*)(ws + 32 * MB);   //  8 MB proj partial (alias qkvb)
  uint16_t* pp1    = (uint16_t*)(ws + 40 * MB);   //  8 MB proj partial
  uint16_t* actb   = (uint16_t*)(ws + 32 * MB);   // 32 MB fc1 out (alias qkvb/vTb)
  uint16_t* fp0    = (uint16_t*)(ws + 16 * MB);   //  8 MB fc2 partial (alias wTqkv/proj)
  uint16_t* fp1    = (uint16_t*)(ws + 24 * MB);   //  8 MB fc2 partial (alias hbuf)

  // prep: all 4 weight transposes + LN1 in one dispatch
  k_prep<<<4096, 256, 0, stream>>>(w_qkv, w_proj, w_fc1, w_fc2,
                                   wTqkv, wTproj, wTfc1, wTfc2,
                                   x, ln1_g, ln1_b, hbuf);

  // qkv GEMM: Q/K cols -> qkvb, V cols -> vTb (transposed in-epilogue)
  k_gemm<3><<<dim3(24, 32), 256, 0, stream>>>(hbuf, wTqkv, b_qkv, qkvb, vTb, 4096, 3072, 1024);
  k_attn<<<dim3(32, 32), 256, 0, stream>>>(qkvb, vTb, ctxb);

  // proj: partials (split-K=2), reduced inside ln2_fuse
  k_gemm_splitk<<<dim3(8, 32, 2), 256, 0, stream>>>(ctxb, wTproj, pp0, pp1,
                                                    4096, 1024, 1024, 512);
  k_ln2_fuse<<<1024, 256, 0, stream>>>(x, pp0, pp1, b_proj, ln2_g, ln2_b, x2b, hbuf);

  k_gemm<2><<<dim3(32, 32), 256, 0, stream>>>(hbuf, wTfc1, b_fc1, actb, nullptr, 4096, 4096, 1024);

  // fc2: partials (split-K=2, Kc=2048), reduced with residual+bias into out
  k_gemm_splitk<<<dim3(8, 32, 2), 256, 0, stream>>>(actb, wTfc2, fp0, fp1,
                                                    4096, 1024, 4096, 2048);
  k_fc2_reduce<<<4096, 256, 0, stream>>>(x2b, fp0, fp1, b_fc2, out, 1024);
}